// Round 2
// baseline (16285.355 us; speedup 1.0000x reference)
//
#include <hip/hip_runtime.h>
#include <math.h>

#define D_      512
#define NPATCH  56
#define DFF_    2048
#define NLAYER  6
#define HEADS   8
#define DH_     64
#define HOR_    24
#define BATCH_  512

// ---------------- block-wide sum over 256 threads (4 waves of 64) ----------------
__device__ __forceinline__ float block_sum256(float v) {
    __shared__ float sm[4];
    const int lane = threadIdx.x & 63;
    const int w    = threadIdx.x >> 6;
    #pragma unroll
    for (int o = 32; o > 0; o >>= 1) v += __shfl_down(v, o);
    __syncthreads();                 // protect sm reuse across calls
    if (lane == 0) sm[w] = v;
    __syncthreads();
    return sm[0] + sm[1] + sm[2] + sm[3];
}

// ---------------- patch embedding: x(chunkTok, 72) @ W(72,512) + b + pos ----------------
__global__ __launch_bounds__(256) void patch_embed_k(
    const float* __restrict__ x, const float* __restrict__ W,
    const float* __restrict__ pb, const float* __restrict__ pos,
    float* __restrict__ h)
{
    const int row = blockIdx.x;          // local token index within chunk
    const int p   = row % NPATCH;
    __shared__ float xs[72];
    const int tid = threadIdx.x;
    if (tid < 72) xs[tid] = x[(size_t)row * 72 + tid];
    __syncthreads();
    for (int d = tid; d < D_; d += 256) {
        float acc = 0.f;
        #pragma unroll
        for (int i = 0; i < 72; i++) acc = fmaf(xs[i], W[i * D_ + d], acc);
        h[(size_t)row * D_ + d] = acc + pb[d] + pos[p * D_ + d];
    }
}

// ---------------- LayerNorm over D=512, one row per block ----------------
__global__ __launch_bounds__(256) void layernorm_k(
    const float* __restrict__ x, const float* __restrict__ g,
    const float* __restrict__ b, float* __restrict__ y)
{
    const size_t row = blockIdx.x;
    const float* xr = x + row * D_;
    float* yr = y + row * D_;
    const int tid = threadIdx.x;
    const float v0 = xr[tid], v1 = xr[tid + 256];
    const float mean = block_sum256(v0 + v1) * (1.f / 512.f);
    const float d0 = v0 - mean, d1 = v1 - mean;
    const float var = block_sum256(d0 * d0 + d1 * d1) * (1.f / 512.f);
    const float rstd = rsqrtf(var + 1e-5f);
    yr[tid]       = d0 * rstd * g[tid]       + b[tid];
    yr[tid + 256] = d1 * rstd * g[tid + 256] + b[tid + 256];
}

// ---------------- fp32 GEMM: C[M,N] = A[M,K] @ W[K,N] + bias (+GELU) (+resid) ----------------
// BM=BN=128, BK=16, 256 threads, 8x8 per thread. M%128==0, N%128==0, K%16==0.
template<bool GELU, bool RESID>
__global__ __launch_bounds__(256, 2) void gemm_f32(
    const float* __restrict__ A, const float* __restrict__ W,
    const float* __restrict__ bias, const float* __restrict__ resid,
    float* __restrict__ C, int M, int N, int K)
{
    __shared__ float As[128][17];   // [m][k], +1 pad breaks row-stride bank aliasing
    __shared__ float Bs[16][128];   // [k][n]
    const int n0 = blockIdx.x * 128;
    const int m0 = blockIdx.y * 128;
    const int tid = threadIdx.x;
    const int tx = tid & 15;        // col group (8 cols each)
    const int ty = tid >> 4;        // row group (8 rows each)

    float acc[8][8];
    #pragma unroll
    for (int i = 0; i < 8; i++)
        #pragma unroll
        for (int j = 0; j < 8; j++) acc[i][j] = 0.f;

    for (int k0 = 0; k0 < K; k0 += 16) {
        #pragma unroll
        for (int t = 0; t < 2; t++) {
            const int f4 = tid + t * 256;
            const int row = f4 >> 2;
            const int c4 = (f4 & 3) << 2;
            const float4 va = *reinterpret_cast<const float4*>(
                &A[(size_t)(m0 + row) * K + k0 + c4]);
            As[row][c4 + 0] = va.x; As[row][c4 + 1] = va.y;
            As[row][c4 + 2] = va.z; As[row][c4 + 3] = va.w;
        }
        #pragma unroll
        for (int t = 0; t < 2; t++) {
            const int f4 = tid + t * 256;
            const int row = f4 >> 5;
            const int c4 = (f4 & 31) << 2;
            *reinterpret_cast<float4*>(&Bs[row][c4]) =
                *reinterpret_cast<const float4*>(&W[(size_t)(k0 + row) * N + n0 + c4]);
        }
        __syncthreads();
        #pragma unroll
        for (int kk = 0; kk < 16; kk++) {
            float a[8], b[8];
            #pragma unroll
            for (int i = 0; i < 8; i++) a[i] = As[ty * 8 + i][kk];
            const float4 b0 = *reinterpret_cast<const float4*>(&Bs[kk][tx * 8]);
            const float4 b1 = *reinterpret_cast<const float4*>(&Bs[kk][tx * 8 + 4]);
            b[0] = b0.x; b[1] = b0.y; b[2] = b0.z; b[3] = b0.w;
            b[4] = b1.x; b[5] = b1.y; b[6] = b1.z; b[7] = b1.w;
            #pragma unroll
            for (int i = 0; i < 8; i++)
                #pragma unroll
                for (int j = 0; j < 8; j++)
                    acc[i][j] = fmaf(a[i], b[j], acc[i][j]);
        }
        __syncthreads();
    }

    #pragma unroll
    for (int i = 0; i < 8; i++) {
        const int row = m0 + ty * 8 + i;
        #pragma unroll
        for (int j = 0; j < 8; j++) {
            const int col = n0 + tx * 8 + j;
            float c = acc[i][j] + bias[col];
            if (GELU) {
                const float xg = c;
                c = 0.5f * xg * (1.f + tanhf(0.7978845608028654f *
                        (xg + 0.044715f * xg * xg * xg)));
            }
            if (RESID) c += resid[(size_t)row * N + col];
            C[(size_t)row * N + col] = c;
        }
    }
}

// ---------------- attention: one block per (batch-row-in-chunk, head) ----------------
__global__ __launch_bounds__(256) void attn_k(
    const float* __restrict__ q, const float* __restrict__ k,
    const float* __restrict__ v, float* __restrict__ o)
{
    const int bh = blockIdx.x;
    const int b  = bh >> 3;          // local batch row
    const int hh = bh & 7;
    __shared__ float qs[NPATCH][DH_];
    __shared__ float ks[NPATCH][DH_ + 1];
    __shared__ float vs[NPATCH][DH_];
    __shared__ float sc[NPATCH][NPATCH + 1];
    const size_t base = (size_t)b * NPATCH * D_ + (size_t)hh * DH_;
    const int tid = threadIdx.x;

    for (int idx = tid; idx < NPATCH * DH_; idx += 256) {
        const int p = idx >> 6, d = idx & 63;
        const size_t off = base + (size_t)p * D_ + d;
        qs[p][d] = q[off];
        ks[p][d] = k[off];
        vs[p][d] = v[off];
    }
    __syncthreads();

    const float slope = exp2f(-(float)(hh + 1));   // 2^(-8h/H), h=1..8
    for (int idx = tid; idx < NPATCH * NPATCH; idx += 256) {
        const int qi = idx / NPATCH, ki = idx % NPATCH;
        float acc = 0.f;
        #pragma unroll
        for (int d0 = 0; d0 < DH_; d0++) acc = fmaf(qs[qi][d0], ks[ki][d0], acc);
        sc[qi][ki] = acc * 0.125f - slope * fabsf((float)(qi - ki));
    }
    __syncthreads();

    if (tid < NPATCH) {
        float m = -1e30f;
        for (int j = 0; j < NPATCH; j++) m = fmaxf(m, sc[tid][j]);
        float s = 0.f;
        for (int j = 0; j < NPATCH; j++) { const float e = expf(sc[tid][j] - m); sc[tid][j] = e; s += e; }
        const float inv = 1.f / s;
        for (int j = 0; j < NPATCH; j++) sc[tid][j] *= inv;
    }
    __syncthreads();

    for (int idx = tid; idx < NPATCH * DH_; idx += 256) {
        const int qi = idx >> 6, d = idx & 63;
        float acc = 0.f;
        #pragma unroll
        for (int kk = 0; kk < NPATCH; kk++) acc = fmaf(sc[qi][kk], vs[kk][d], acc);
        o[base + (size_t)qi * D_ + d] = acc;
    }
}

// ---------------- mean pool over NP ----------------
__global__ __launch_bounds__(256) void meanpool_k(
    const float* __restrict__ h, float* __restrict__ pooled)
{
    const int b = blockIdx.x;        // local batch row
    for (int d = threadIdx.x; d < D_; d += 256) {
        float acc = 0.f;
        #pragma unroll
        for (int p = 0; p < NPATCH; p++)
            acc += h[(size_t)b * NPATCH * D_ + (size_t)p * D_ + d];
        pooled[(size_t)b * D_ + d] = acc * (1.f / (float)NPATCH);
    }
}

// ---------------- final LN + head: one block per batch row ----------------
__global__ __launch_bounds__(256) void head_k(
    const float* __restrict__ pooled, const float* __restrict__ g,
    const float* __restrict__ bb, const float* __restrict__ hW,
    const float* __restrict__ hb, float* __restrict__ out)
{
    const int b = blockIdx.x;        // local batch row
    __shared__ float row[D_];
    const int tid = threadIdx.x;
    const float v0 = pooled[(size_t)b * D_ + tid];
    const float v1 = pooled[(size_t)b * D_ + tid + 256];
    const float mean = block_sum256(v0 + v1) * (1.f / 512.f);
    const float d0 = v0 - mean, d1 = v1 - mean;
    const float var = block_sum256(d0 * d0 + d1 * d1) * (1.f / 512.f);
    const float rstd = rsqrtf(var + 1e-5f);
    row[tid]       = d0 * rstd * g[tid]       + bb[tid];
    row[tid + 256] = d1 * rstd * g[tid + 256] + bb[tid + 256];
    __syncthreads();
    if (tid < HOR_) {
        float acc = hb[tid];
        for (int kk = 0; kk < D_; kk++) acc = fmaf(row[kk], hW[kk * HOR_ + tid], acc);
        out[(size_t)b * HOR_ + tid] = acc;
    }
}

extern "C" void kernel_launch(void* const* d_in, const int* in_sizes, int n_in,
                              void* d_out, int out_size, void* d_ws, size_t ws_size,
                              hipStream_t stream)
{
    const float* x       = (const float*)d_in[0];
    const float* patch_W = (const float*)d_in[1];
    const float* patch_b = (const float*)d_in[2];
    const float* pos     = (const float*)d_in[3];
    const float* ln1_g   = (const float*)d_in[4];
    const float* ln1_b   = (const float*)d_in[5];
    const float* Wq      = (const float*)d_in[6];
    const float* bq      = (const float*)d_in[7];
    const float* Wk      = (const float*)d_in[8];
    const float* bk      = (const float*)d_in[9];
    const float* Wv      = (const float*)d_in[10];
    const float* bv      = (const float*)d_in[11];
    const float* Wo      = (const float*)d_in[12];
    const float* bo      = (const float*)d_in[13];
    const float* ln2_g   = (const float*)d_in[14];
    const float* ln2_b   = (const float*)d_in[15];
    const float* W1      = (const float*)d_in[16];
    const float* b1      = (const float*)d_in[17];
    const float* W2      = (const float*)d_in[18];
    const float* b2      = (const float*)d_in[19];
    const float* fn_g    = (const float*)d_in[20];
    const float* fn_b    = (const float*)d_in[21];
    const float* head_W  = (const float*)d_in[22];
    const float* head_b  = (const float*)d_in[23];
    float* out = (float*)d_out;

    // ---- choose batch-chunk size so the workspace fits ws_size ----
    // per-chunk floats: 6 * (BC*56*512) + BC*512   (h, hn, q, k, v, ao, pooled)
    int BC = 16;
    for (int cand = BATCH_; cand >= 16; cand >>= 1) {
        const size_t need = ((size_t)6 * cand * NPATCH * D_ + (size_t)cand * D_) * sizeof(float);
        if (need <= ws_size) { BC = cand; break; }
    }
    const int nChunks = BATCH_ / BC;
    const int CT = BC * NPATCH;               // tokens per chunk (multiple of 128)
    const size_t TD = (size_t)CT * D_;

    float* ws  = (float*)d_ws;
    float* h      = ws;            // [CT, D]
    float* hn     = h  + TD;       // [CT, D]
    float* q      = hn + TD;       // [CT, D]
    float* k      = q  + TD;       // [CT, D]
    float* v      = k  + TD;       // [CT, D]
    float* ao     = v  + TD;       // [CT, D]
    float* mid    = q;             // aliases q..ao: 4*TD == CT*DFF exactly
    float* pooled = ao + TD;       // [BC, D]

    const dim3 g1(D_ / 128, CT / 128);
    const dim3 g2(DFF_ / 128, CT / 128);

    for (int c = 0; c < nChunks; c++) {
        const size_t tok0 = (size_t)c * CT;

        patch_embed_k<<<CT, 256, 0, stream>>>(
            x + tok0 * 72, patch_W, patch_b, pos, h);

        for (int l = 0; l < NLAYER; l++) {
            layernorm_k<<<CT, 256, 0, stream>>>(h, ln1_g + l * D_, ln1_b + l * D_, hn);
            gemm_f32<false, false><<<g1, 256, 0, stream>>>(
                hn, Wq + (size_t)l * D_ * D_, bq + l * D_, nullptr, q, CT, D_, D_);
            gemm_f32<false, false><<<g1, 256, 0, stream>>>(
                hn, Wk + (size_t)l * D_ * D_, bk + l * D_, nullptr, k, CT, D_, D_);
            gemm_f32<false, false><<<g1, 256, 0, stream>>>(
                hn, Wv + (size_t)l * D_ * D_, bv + l * D_, nullptr, v, CT, D_, D_);
            attn_k<<<BC * HEADS, 256, 0, stream>>>(q, k, v, ao);
            gemm_f32<false, true><<<g1, 256, 0, stream>>>(
                ao, Wo + (size_t)l * D_ * D_, bo + l * D_, h, h, CT, D_, D_);
            layernorm_k<<<CT, 256, 0, stream>>>(h, ln2_g + l * D_, ln2_b + l * D_, hn);
            gemm_f32<true, false><<<g2, 256, 0, stream>>>(
                hn, W1 + (size_t)l * D_ * DFF_, b1 + l * DFF_, nullptr, mid, CT, DFF_, D_);
            gemm_f32<false, true><<<g1, 256, 0, stream>>>(
                mid, W2 + (size_t)l * DFF_ * D_, b2 + l * D_, h, h, CT, D_, DFF_);
        }

        meanpool_k<<<BC, 256, 0, stream>>>(h, pooled);
        head_k<<<BC, 256, 0, stream>>>(pooled, fn_g, fn_b, head_W, head_b,
                                       out + tok0 / NPATCH * HOR_);
    }
}

// Round 3
// 4090.142 us; speedup vs baseline: 3.9816x; 3.9816x over previous
//
#include <hip/hip_runtime.h>
#include <hip/hip_bf16.h>
#include <math.h>

#define D_      512
#define NPATCH  56
#define DFF_    2048
#define NLAYER  6
#define HEADS   8
#define DH_     64
#define HOR_    24
#define BATCH_  512

typedef __hip_bfloat16 bf16;
typedef __bf16 bf16x8 __attribute__((ext_vector_type(8)));
typedef float  f32x4  __attribute__((ext_vector_type(4)));

// async global->LDS, 16 bytes per lane. LDS dest = wave-uniform base + lane*16.
__device__ __forceinline__ void gload_lds16(const void* g, void* lds) {
    __builtin_amdgcn_global_load_lds(
        (const __attribute__((address_space(1))) unsigned int*)g,
        (__attribute__((address_space(3))) unsigned int*)lds, 16, 0, 0);
}

// ---------------- block-wide sum over 256 threads ----------------
__device__ __forceinline__ float block_sum256(float v) {
    __shared__ float sm[4];
    const int lane = threadIdx.x & 63;
    const int w    = threadIdx.x >> 6;
    #pragma unroll
    for (int o = 32; o > 0; o >>= 1) v += __shfl_down(v, o);
    __syncthreads();
    if (lane == 0) sm[w] = v;
    __syncthreads();
    return sm[0] + sm[1] + sm[2] + sm[3];
}

// ---------------- transpose + fp32->bf16: in[R][C] -> out[C][R], one layer per blockIdx.z ----------------
__global__ __launch_bounds__(256) void transpose_bf16_k(
    const float* __restrict__ in, bf16* __restrict__ out, int R, int C)
{
    __shared__ float t[32][33];
    const size_t off = (size_t)blockIdx.z * R * C;
    in += off; out += off;
    const int c0 = blockIdx.x * 32, r0 = blockIdx.y * 32;
    const int x = threadIdx.x & 31, y = threadIdx.x >> 5;   // x:0-31, y:0-7
    #pragma unroll
    for (int i = 0; i < 4; i++)
        t[y + i * 8][x] = in[(size_t)(r0 + y + i * 8) * C + c0 + x];
    __syncthreads();
    #pragma unroll
    for (int i = 0; i < 4; i++)
        out[(size_t)(c0 + y + i * 8) * R + r0 + x] = __float2bfloat16(t[x][y + i * 8]);
}

// ---------------- patch embedding (fp32) ----------------
__global__ __launch_bounds__(256) void patch_embed_k(
    const float* __restrict__ x, const float* __restrict__ W,
    const float* __restrict__ pb, const float* __restrict__ pos,
    float* __restrict__ h)
{
    const int row = blockIdx.x;
    const int p   = row % NPATCH;
    __shared__ float xs[72];
    const int tid = threadIdx.x;
    if (tid < 72) xs[tid] = x[(size_t)row * 72 + tid];
    __syncthreads();
    for (int d = tid; d < D_; d += 256) {
        float acc = 0.f;
        #pragma unroll
        for (int i = 0; i < 72; i++) acc = fmaf(xs[i], W[i * D_ + d], acc);
        h[(size_t)row * D_ + d] = acc + pb[d] + pos[p * D_ + d];
    }
}

// ---------------- LayerNorm fp32 in -> bf16 out ----------------
__global__ __launch_bounds__(256) void layernorm_bf16_k(
    const float* __restrict__ x, const float* __restrict__ g,
    const float* __restrict__ b, bf16* __restrict__ y)
{
    const size_t row = blockIdx.x;
    const float* xr = x + row * D_;
    bf16* yr = y + row * D_;
    const int tid = threadIdx.x;
    const float v0 = xr[tid], v1 = xr[tid + 256];
    const float mean = block_sum256(v0 + v1) * (1.f / 512.f);
    const float d0 = v0 - mean, d1 = v1 - mean;
    const float var = block_sum256(d0 * d0 + d1 * d1) * (1.f / 512.f);
    const float rstd = rsqrtf(var + 1e-5f);
    yr[tid]       = __float2bfloat16(d0 * rstd * g[tid]       + b[tid]);
    yr[tid + 256] = __float2bfloat16(d1 * rstd * g[tid + 256] + b[tid + 256]);
}

// ---------------- bf16 MFMA GEMM (m97 structure): C[M,N] = A[M,K] @ Bt[N,K]^T ----------------
// 128x128 tile, BK=32, 4 waves each computing a 64x64 sub-tile (4x4 fragments of 16x16x32).
template<bool OUT_BF16, bool GELU, bool RESID>
__global__ __launch_bounds__(256, 2) void gemm_bf16_k(
    const bf16* __restrict__ A, const bf16* __restrict__ Bt,
    const float* __restrict__ bias, const float* __restrict__ resid,
    void* __restrict__ Cp, int M, int N, int K)
{
    __shared__ __align__(16) bf16 As[128 * 32];
    __shared__ __align__(16) bf16 Bs[128 * 32];
    const int tid  = threadIdx.x;
    const int wid  = tid >> 6;
    const int lane = tid & 63;
    const int n0 = blockIdx.x * 128;
    const int m0 = blockIdx.y * 128;
    const int wr = wid >> 1, wc = wid & 1;

    f32x4 acc[4][4];
    #pragma unroll
    for (int m = 0; m < 4; m++)
        #pragma unroll
        for (int n = 0; n < 4; n++) acc[m][n] = f32x4{0.f, 0.f, 0.f, 0.f};

    // staging: wave w issues 2 loads for A, 2 for B; instr (w*2+t) covers 16 tile rows.
    const int rstage = wid * 32 + (lane >> 2);  // tile row for t=0 (t=1 adds 16)
    const int cstage = (lane & 3) * 8;          // k-offset elems (16B chunk)
    const bf16* gA = A  + (size_t)(m0 + rstage) * K + cstage;
    const bf16* gB = Bt + (size_t)(n0 + rstage) * K + cstage;
    bf16* lA0 = &As[(wid * 2 + 0) * 512];
    bf16* lA1 = &As[(wid * 2 + 1) * 512];
    bf16* lB0 = &Bs[(wid * 2 + 0) * 512];
    bf16* lB1 = &Bs[(wid * 2 + 1) * 512];
    const size_t k16 = (size_t)16 * K;

    // fragment read offsets: lane l -> row (l&15), k-chunk (l>>4)*8
    const int fr = lane & 15;
    const int kc = (lane >> 4) * 8;
    const int abase = (wr * 64 + fr) * 32 + kc;
    const int bbase = (wc * 64 + fr) * 32 + kc;

    for (int k0 = 0; k0 < K; k0 += 32) {
        gload_lds16(gA + k0,       lA0);
        gload_lds16(gA + k0 + k16, lA1);
        gload_lds16(gB + k0,       lB0);
        gload_lds16(gB + k0 + k16, lB1);
        __syncthreads();             // drains vmcnt, loads visible to all
        bf16x8 af[4], bg[4];
        #pragma unroll
        for (int m = 0; m < 4; m++) af[m] = *(const bf16x8*)&As[abase + m * 512];
        #pragma unroll
        for (int n = 0; n < 4; n++) bg[n] = *(const bf16x8*)&Bs[bbase + n * 512];
        #pragma unroll
        for (int m = 0; m < 4; m++)
            #pragma unroll
            for (int n = 0; n < 4; n++)
                acc[m][n] = __builtin_amdgcn_mfma_f32_16x16x32_bf16(af[m], bg[n], acc[m][n], 0, 0, 0);
        __syncthreads();             // reads done before next-iter staging overwrites
    }

    // epilogue: C/D layout col=lane&15, row=(lane>>4)*4+j  [m89/m91 verified]
    const int rq = (lane >> 4) * 4;
    #pragma unroll
    for (int m = 0; m < 4; m++) {
        #pragma unroll
        for (int n = 0; n < 4; n++) {
            const int col = n0 + wc * 64 + n * 16 + fr;
            const float bcol = bias[col];
            #pragma unroll
            for (int j = 0; j < 4; j++) {
                const int row = m0 + wr * 64 + m * 16 + rq + j;
                float c = acc[m][n][j] + bcol;
                if (GELU) {
                    const float xg = c;
                    c = 0.5f * xg * (1.f + tanhf(0.7978845608028654f *
                            (xg + 0.044715f * xg * xg * xg)));
                }
                if (RESID) c += resid[(size_t)row * N + col];
                if (OUT_BF16) ((bf16*)Cp)[(size_t)row * N + col] = __float2bfloat16(c);
                else          ((float*)Cp)[(size_t)row * N + col] = c;
            }
        }
    }
}

// ---------------- attention (fp32 q/k/v in, bf16 out): one block per (row, head) ----------------
__global__ __launch_bounds__(256) void attn_k(
    const float* __restrict__ q, const float* __restrict__ k,
    const float* __restrict__ v, bf16* __restrict__ o)
{
    const int bh = blockIdx.x;
    const int b  = bh >> 3;
    const int hh = bh & 7;
    __shared__ float qs[NPATCH][DH_];
    __shared__ float ks[NPATCH][DH_ + 1];
    __shared__ float vs[NPATCH][DH_];
    __shared__ float sc[NPATCH][NPATCH + 1];
    const size_t base = (size_t)b * NPATCH * D_ + (size_t)hh * DH_;
    const int tid = threadIdx.x;

    for (int idx = tid; idx < NPATCH * DH_; idx += 256) {
        const int p = idx >> 6, d = idx & 63;
        const size_t off = base + (size_t)p * D_ + d;
        qs[p][d] = q[off];
        ks[p][d] = k[off];
        vs[p][d] = v[off];
    }
    __syncthreads();

    const float slope = exp2f(-(float)(hh + 1));
    for (int idx = tid; idx < NPATCH * NPATCH; idx += 256) {
        const int qi = idx / NPATCH, ki = idx % NPATCH;
        float acc = 0.f;
        #pragma unroll
        for (int d0 = 0; d0 < DH_; d0++) acc = fmaf(qs[qi][d0], ks[ki][d0], acc);
        sc[qi][ki] = acc * 0.125f - slope * fabsf((float)(qi - ki));
    }
    __syncthreads();

    if (tid < NPATCH) {
        float m = -1e30f;
        for (int j = 0; j < NPATCH; j++) m = fmaxf(m, sc[tid][j]);
        float s = 0.f;
        for (int j = 0; j < NPATCH; j++) { const float e = expf(sc[tid][j] - m); sc[tid][j] = e; s += e; }
        const float inv = 1.f / s;
        for (int j = 0; j < NPATCH; j++) sc[tid][j] *= inv;
    }
    __syncthreads();

    for (int idx = tid; idx < NPATCH * DH_; idx += 256) {
        const int qi = idx >> 6, d = idx & 63;
        float acc = 0.f;
        #pragma unroll
        for (int kk = 0; kk < NPATCH; kk++) acc = fmaf(sc[qi][kk], vs[kk][d], acc);
        o[base + (size_t)qi * D_ + d] = __float2bfloat16(acc);
    }
}

// ---------------- mean pool ----------------
__global__ __launch_bounds__(256) void meanpool_k(
    const float* __restrict__ h, float* __restrict__ pooled)
{
    const int b = blockIdx.x;
    for (int d = threadIdx.x; d < D_; d += 256) {
        float acc = 0.f;
        #pragma unroll
        for (int p = 0; p < NPATCH; p++)
            acc += h[(size_t)b * NPATCH * D_ + (size_t)p * D_ + d];
        pooled[(size_t)b * D_ + d] = acc * (1.f / (float)NPATCH);
    }
}

// ---------------- final LN + head ----------------
__global__ __launch_bounds__(256) void head_k(
    const float* __restrict__ pooled, const float* __restrict__ g,
    const float* __restrict__ bb, const float* __restrict__ hW,
    const float* __restrict__ hb, float* __restrict__ out)
{
    const int b = blockIdx.x;
    __shared__ float row[D_];
    const int tid = threadIdx.x;
    const float v0 = pooled[(size_t)b * D_ + tid];
    const float v1 = pooled[(size_t)b * D_ + tid + 256];
    const float mean = block_sum256(v0 + v1) * (1.f / 512.f);
    const float d0 = v0 - mean, d1 = v1 - mean;
    const float var = block_sum256(d0 * d0 + d1 * d1) * (1.f / 512.f);
    const float rstd = rsqrtf(var + 1e-5f);
    row[tid]       = d0 * rstd * g[tid]       + bb[tid];
    row[tid + 256] = d1 * rstd * g[tid + 256] + bb[tid + 256];
    __syncthreads();
    if (tid < HOR_) {
        float acc = hb[tid];
        for (int kk = 0; kk < D_; kk++) acc = fmaf(row[kk], hW[kk * HOR_ + tid], acc);
        out[(size_t)b * HOR_ + tid] = acc;
    }
}

extern "C" void kernel_launch(void* const* d_in, const int* in_sizes, int n_in,
                              void* d_out, int out_size, void* d_ws, size_t ws_size,
                              hipStream_t stream)
{
    const float* x       = (const float*)d_in[0];
    const float* patch_W = (const float*)d_in[1];
    const float* patch_b = (const float*)d_in[2];
    const float* pos     = (const float*)d_in[3];
    const float* ln1_g   = (const float*)d_in[4];
    const float* ln1_b   = (const float*)d_in[5];
    const float* Wq      = (const float*)d_in[6];
    const float* bq      = (const float*)d_in[7];
    const float* Wk      = (const float*)d_in[8];
    const float* bk      = (const float*)d_in[9];
    const float* Wv      = (const float*)d_in[10];
    const float* bv      = (const float*)d_in[11];
    const float* Wo      = (const float*)d_in[12];
    const float* bo      = (const float*)d_in[13];
    const float* ln2_g   = (const float*)d_in[14];
    const float* ln2_b   = (const float*)d_in[15];
    const float* W1      = (const float*)d_in[16];
    const float* b1      = (const float*)d_in[17];
    const float* W2      = (const float*)d_in[18];
    const float* b2      = (const float*)d_in[19];
    const float* fn_g    = (const float*)d_in[20];
    const float* fn_b    = (const float*)d_in[21];
    const float* head_W  = (const float*)d_in[22];
    const float* head_b  = (const float*)d_in[23];
    float* out = (float*)d_out;

    // ---- workspace: bf16 transposed weights first (fixed 37,748,736 B), then activations ----
    const size_t WELEM  = (size_t)D_ * D_;          // 262144
    const size_t WFELEM = (size_t)D_ * DFF_;        // 1048576
    bf16* wqt = (bf16*)d_ws;                        // [6][512][512]   (N,K)
    bf16* wkt = wqt + NLAYER * WELEM;
    bf16* wvt = wkt + NLAYER * WELEM;
    bf16* wot = wvt + NLAYER * WELEM;
    bf16* w1t = wot + NLAYER * WELEM;               // [6][2048][512]
    bf16* w2t = w1t + NLAYER * WFELEM;              // [6][512][2048]
    char* wend = (char*)(w2t + NLAYER * WFELEM);
    const size_t WBYTES = (size_t)(wend - (char*)d_ws);

    // ---- batch-chunk size: per-token activation bytes = 2048(h) + 1024(hn) + 6144(qkv) + 1024(ao) ----
    int BC = 16;
    for (int cand = BATCH_; cand >= 16; cand >>= 1) {
        const size_t need = WBYTES + (size_t)cand * NPATCH * 10240 + (size_t)cand * 2048;
        if (need <= ws_size) { BC = cand; break; }
    }
    const int nChunks = BATCH_ / BC;
    const int CT = BC * NPATCH;                     // multiple of 128 for BC>=16
    const size_t TD = (size_t)CT * D_;

    float* h   = (float*)wend;          // [CT][512] f32
    bf16*  hn  = (bf16*)(h + TD);       // [CT][512] bf16
    float* q   = (float*)(hn + TD);     // [CT][512] f32
    float* kbuf= q + TD;
    float* v   = kbuf + TD;
    bf16*  ao  = (bf16*)(v + TD);       // [CT][512] bf16
    bf16*  mid = (bf16*)q;              // [CT][2048] bf16, aliases q..kbuf (dead then)
    float* pooled = (float*)(ao + TD);  // [BC][512]

    // ---- weight convert+transpose (once per call) ----
    transpose_bf16_k<<<dim3(D_ / 32, D_ / 32, NLAYER), 256, 0, stream>>>(Wq, wqt, D_, D_);
    transpose_bf16_k<<<dim3(D_ / 32, D_ / 32, NLAYER), 256, 0, stream>>>(Wk, wkt, D_, D_);
    transpose_bf16_k<<<dim3(D_ / 32, D_ / 32, NLAYER), 256, 0, stream>>>(Wv, wvt, D_, D_);
    transpose_bf16_k<<<dim3(D_ / 32, D_ / 32, NLAYER), 256, 0, stream>>>(Wo, wot, D_, D_);
    transpose_bf16_k<<<dim3(DFF_ / 32, D_ / 32, NLAYER), 256, 0, stream>>>(W1, w1t, D_, DFF_);
    transpose_bf16_k<<<dim3(D_ / 32, DFF_ / 32, NLAYER), 256, 0, stream>>>(W2, w2t, DFF_, D_);

    const dim3 g1(D_ / 128, CT / 128);
    const dim3 g2(DFF_ / 128, CT / 128);

    for (int c = 0; c < nChunks; c++) {
        const size_t tok0 = (size_t)c * CT;

        patch_embed_k<<<CT, 256, 0, stream>>>(x + tok0 * 72, patch_W, patch_b, pos, h);

        for (int l = 0; l < NLAYER; l++) {
            layernorm_bf16_k<<<CT, 256, 0, stream>>>(h, ln1_g + l * D_, ln1_b + l * D_, hn);
            gemm_bf16_k<false, false, false><<<g1, 256, 0, stream>>>(
                hn, wqt + l * WELEM, bq + l * D_, nullptr, q, CT, D_, D_);
            gemm_bf16_k<false, false, false><<<g1, 256, 0, stream>>>(
                hn, wkt + l * WELEM, bk + l * D_, nullptr, kbuf, CT, D_, D_);
            gemm_bf16_k<false, false, false><<<g1, 256, 0, stream>>>(
                hn, wvt + l * WELEM, bv + l * D_, nullptr, v, CT, D_, D_);
            attn_k<<<BC * HEADS, 256, 0, stream>>>(q, kbuf, v, ao);
            gemm_bf16_k<false, false, true><<<g1, 256, 0, stream>>>(
                ao, wot + l * WELEM, bo + l * D_, h, h, CT, D_, D_);
            layernorm_bf16_k<<<CT, 256, 0, stream>>>(h, ln2_g + l * D_, ln2_b + l * D_, hn);
            gemm_bf16_k<true, true, false><<<g2, 256, 0, stream>>>(
                hn, w1t + l * WFELEM, b1 + l * DFF_, nullptr, mid, CT, DFF_, D_);
            gemm_bf16_k<false, false, true><<<g1, 256, 0, stream>>>(
                mid, w2t + l * WFELEM, b2 + l * D_, h, h, CT, D_, DFF_);
        }

        meanpool_k<<<BC, 256, 0, stream>>>(h, pooled);
        head_k<<<BC, 256, 0, stream>>>(pooled, fn_g, fn_b, head_W, head_b,
                                       out + (size_t)c * BC * HOR_);
    }
}

// Round 4
// 3356.138 us; speedup vs baseline: 4.8524x; 1.2187x over previous
//
#include <hip/hip_runtime.h>
#include <hip/hip_bf16.h>
#include <math.h>

#define D_      512
#define NPATCH  56
#define DFF_    2048
#define NLAYER  6
#define HEADS   8
#define DH_     64
#define HOR_    24
#define BATCH_  512
#define NTOK_   (BATCH_ * NPATCH)
#define KPAD    96                  // patch K=72 padded to 96 (mult of 32)

typedef __hip_bfloat16 bf16;
typedef __bf16 bf16x8 __attribute__((ext_vector_type(8)));
typedef float  f32x4  __attribute__((ext_vector_type(4)));

__device__ __forceinline__ void gload_lds16(const void* g, void* lds) {
    __builtin_amdgcn_global_load_lds(
        (const __attribute__((address_space(1))) unsigned int*)g,
        (__attribute__((address_space(3))) unsigned int*)lds, 16, 0, 0);
}

// ---------------- block-wide sum over 256 threads ----------------
__device__ __forceinline__ float block_sum256(float v) {
    __shared__ float sm[4];
    const int lane = threadIdx.x & 63;
    const int w    = threadIdx.x >> 6;
    #pragma unroll
    for (int o = 32; o > 0; o >>= 1) v += __shfl_down(v, o);
    __syncthreads();
    if (lane == 0) sm[w] = v;
    __syncthreads();
    return sm[0] + sm[1] + sm[2] + sm[3];
}

// ---------------- transpose + fp32->bf16 with independent layer strides ----------------
__global__ __launch_bounds__(256) void transpose_bf16_k(
    const float* __restrict__ in, bf16* __restrict__ out, int R, int C,
    size_t in_ls, size_t out_ls)
{
    __shared__ float t[32][33];
    in  += (size_t)blockIdx.z * in_ls;
    out += (size_t)blockIdx.z * out_ls;
    const int c0 = blockIdx.x * 32, r0 = blockIdx.y * 32;
    const int x = threadIdx.x & 31, y = threadIdx.x >> 5;
    #pragma unroll
    for (int i = 0; i < 4; i++)
        t[y + i * 8][x] = in[(size_t)(r0 + y + i * 8) * C + c0 + x];
    __syncthreads();
    #pragma unroll
    for (int i = 0; i < 4; i++)
        out[(size_t)(c0 + y + i * 8) * R + r0 + x] = __float2bfloat16(t[x][y + i * 8]);
}

// ---------------- patch_W [72][512] -> bf16 transposed padded [512][96] ----------------
__global__ __launch_bounds__(256) void pwt_k(
    const float* __restrict__ W, bf16* __restrict__ out)
{
    const int idx = blockIdx.x * 256 + threadIdx.x;     // over 512*96
    if (idx >= D_ * KPAD) return;
    const int n = idx / KPAD, kk = idx % KPAD;
    out[idx] = (kk < 72) ? __float2bfloat16(W[kk * D_ + n]) : __float2bfloat16(0.f);
}

// ---------------- x [NTOK][72] f32 -> [NTOK][96] bf16 zero-padded ----------------
__global__ __launch_bounds__(256) void xpad_k(
    const float* __restrict__ x, bf16* __restrict__ out)
{
    const size_t idx = (size_t)blockIdx.x * 256 + threadIdx.x;  // over NTOK*96
    if (idx >= (size_t)NTOK_ * KPAD) return;
    const size_t row = idx / KPAD;
    const int kk = (int)(idx - row * KPAD);
    out[idx] = (kk < 72) ? __float2bfloat16(x[row * 72 + kk]) : __float2bfloat16(0.f);
}

// ---------------- concat q/k/v biases -> [NL][1536] f32 ----------------
__global__ __launch_bounds__(256) void bqkv_k(
    const float* __restrict__ bq, const float* __restrict__ bk,
    const float* __restrict__ bv, float* __restrict__ o)
{
    const int idx = blockIdx.x * 256 + threadIdx.x;     // over 6*1536
    if (idx >= NLAYER * 3 * D_) return;
    const int l = idx / (3 * D_), n = idx % (3 * D_);
    float v;
    if      (n < D_)     v = bq[l * D_ + n];
    else if (n < 2 * D_) v = bk[l * D_ + n - D_];
    else                 v = bv[l * D_ + n - 2 * D_];
    o[idx] = v;
}

// ---------------- LayerNorm fp32 in -> bf16 out ----------------
__global__ __launch_bounds__(256) void layernorm_bf16_k(
    const float* __restrict__ x, const float* __restrict__ g,
    const float* __restrict__ b, bf16* __restrict__ y)
{
    const size_t row = blockIdx.x;
    const float* xr = x + row * D_;
    bf16* yr = y + row * D_;
    const int tid = threadIdx.x;
    const float v0 = xr[tid], v1 = xr[tid + 256];
    const float mean = block_sum256(v0 + v1) * (1.f / 512.f);
    const float d0 = v0 - mean, d1 = v1 - mean;
    const float var = block_sum256(d0 * d0 + d1 * d1) * (1.f / 512.f);
    const float rstd = rsqrtf(var + 1e-5f);
    yr[tid]       = __float2bfloat16(d0 * rstd * g[tid]       + b[tid]);
    yr[tid + 256] = __float2bfloat16(d1 * rstd * g[tid + 256] + b[tid + 256]);
}

// ---------------- bf16 MFMA GEMM (m97 structure): C[M,N] = A[M,K] @ Bt[N,K]^T ----------------
template<bool OUT_BF16, bool GELU, bool RESID, bool POS>
__global__ __launch_bounds__(256, 2) void gemm_bf16_k(
    const bf16* __restrict__ A, const bf16* __restrict__ Bt,
    const float* __restrict__ bias, const float* __restrict__ resid,
    const float* __restrict__ pos, void* __restrict__ Cp, int M, int N, int K)
{
    __shared__ __align__(16) bf16 As[128 * 32];
    __shared__ __align__(16) bf16 Bs[128 * 32];
    const int tid  = threadIdx.x;
    const int wid  = tid >> 6;
    const int lane = tid & 63;
    const int n0 = blockIdx.x * 128;
    const int m0 = blockIdx.y * 128;
    const int wr = wid >> 1, wc = wid & 1;

    f32x4 acc[4][4];
    #pragma unroll
    for (int m = 0; m < 4; m++)
        #pragma unroll
        for (int n = 0; n < 4; n++) acc[m][n] = f32x4{0.f, 0.f, 0.f, 0.f};

    const int rstage = wid * 32 + (lane >> 2);
    const int cstage = (lane & 3) * 8;
    const bf16* gA = A  + (size_t)(m0 + rstage) * K + cstage;
    const bf16* gB = Bt + (size_t)(n0 + rstage) * K + cstage;
    bf16* lA0 = &As[(wid * 2 + 0) * 512];
    bf16* lA1 = &As[(wid * 2 + 1) * 512];
    bf16* lB0 = &Bs[(wid * 2 + 0) * 512];
    bf16* lB1 = &Bs[(wid * 2 + 1) * 512];
    const size_t k16 = (size_t)16 * K;

    const int fr = lane & 15;
    const int kc = (lane >> 4) * 8;
    const int abase = (wr * 64 + fr) * 32 + kc;
    const int bbase = (wc * 64 + fr) * 32 + kc;

    for (int k0 = 0; k0 < K; k0 += 32) {
        gload_lds16(gA + k0,       lA0);
        gload_lds16(gA + k0 + k16, lA1);
        gload_lds16(gB + k0,       lB0);
        gload_lds16(gB + k0 + k16, lB1);
        __syncthreads();
        bf16x8 af[4], bg[4];
        #pragma unroll
        for (int m = 0; m < 4; m++) af[m] = *(const bf16x8*)&As[abase + m * 512];
        #pragma unroll
        for (int n = 0; n < 4; n++) bg[n] = *(const bf16x8*)&Bs[bbase + n * 512];
        #pragma unroll
        for (int m = 0; m < 4; m++)
            #pragma unroll
            for (int n = 0; n < 4; n++)
                acc[m][n] = __builtin_amdgcn_mfma_f32_16x16x32_bf16(af[m], bg[n], acc[m][n], 0, 0, 0);
        __syncthreads();
    }

    const int rq = (lane >> 4) * 4;
    #pragma unroll
    for (int m = 0; m < 4; m++) {
        #pragma unroll
        for (int n = 0; n < 4; n++) {
            const int col = n0 + wc * 64 + n * 16 + fr;
            const float bcol = bias[col];
            #pragma unroll
            for (int j = 0; j < 4; j++) {
                const int row = m0 + wr * 64 + m * 16 + rq + j;
                float c = acc[m][n][j] + bcol;
                if (GELU) {
                    const float xg = c;
                    c = 0.5f * xg * (1.f + tanhf(0.7978845608028654f *
                            (xg + 0.044715f * xg * xg * xg)));
                }
                if (RESID) c += resid[(size_t)row * N + col];
                if (POS)   c += pos[(size_t)(row % NPATCH) * D_ + col];
                if (OUT_BF16) ((bf16*)Cp)[(size_t)row * N + col] = __float2bfloat16(c);
                else          ((float*)Cp)[(size_t)row * N + col] = c;
            }
        }
    }
}

// ---------------- attention: bf16 qkv [CT][1536] in, bf16 ao out ----------------
__global__ __launch_bounds__(256) void attn_k(
    const bf16* __restrict__ qkv, bf16* __restrict__ o)
{
    const int bh = blockIdx.x;
    const int b  = bh >> 3;
    const int hh = bh & 7;
    __shared__ float qs[NPATCH][DH_];
    __shared__ float ks[NPATCH][DH_ + 1];
    __shared__ float vs[NPATCH][DH_];
    __shared__ float sc[NPATCH][NPATCH + 1];
    const size_t base = (size_t)b * NPATCH * 1536 + (size_t)hh * DH_;
    const int tid = threadIdx.x;

    for (int idx = tid; idx < NPATCH * DH_; idx += 256) {
        const int p = idx >> 6, d = idx & 63;
        const size_t off = base + (size_t)p * 1536 + d;
        qs[p][d] = __bfloat162float(qkv[off]);
        ks[p][d] = __bfloat162float(qkv[off + 512]);
        vs[p][d] = __bfloat162float(qkv[off + 1024]);
    }
    __syncthreads();

    const float slope = exp2f(-(float)(hh + 1));
    for (int idx = tid; idx < NPATCH * NPATCH; idx += 256) {
        const int qi = idx / NPATCH, ki = idx % NPATCH;
        float acc = 0.f;
        #pragma unroll
        for (int d0 = 0; d0 < DH_; d0++) acc = fmaf(qs[qi][d0], ks[ki][d0], acc);
        sc[qi][ki] = acc * 0.125f - slope * fabsf((float)(qi - ki));
    }
    __syncthreads();

    if (tid < NPATCH) {
        float m = -1e30f;
        for (int j = 0; j < NPATCH; j++) m = fmaxf(m, sc[tid][j]);
        float s = 0.f;
        for (int j = 0; j < NPATCH; j++) { const float e = expf(sc[tid][j] - m); sc[tid][j] = e; s += e; }
        const float inv = 1.f / s;
        for (int j = 0; j < NPATCH; j++) sc[tid][j] *= inv;
    }
    __syncthreads();

    const size_t obase = (size_t)b * NPATCH * D_ + (size_t)hh * DH_;
    for (int idx = tid; idx < NPATCH * DH_; idx += 256) {
        const int qi = idx >> 6, d = idx & 63;
        float acc = 0.f;
        #pragma unroll
        for (int kk = 0; kk < NPATCH; kk++) acc = fmaf(sc[qi][kk], vs[kk][d], acc);
        o[obase + (size_t)qi * D_ + d] = __float2bfloat16(acc);
    }
}

// ---------------- mean pool ----------------
__global__ __launch_bounds__(256) void meanpool_k(
    const float* __restrict__ h, float* __restrict__ pooled)
{
    const int b = blockIdx.x;
    for (int d = threadIdx.x; d < D_; d += 256) {
        float acc = 0.f;
        #pragma unroll
        for (int p = 0; p < NPATCH; p++)
            acc += h[(size_t)b * NPATCH * D_ + (size_t)p * D_ + d];
        pooled[(size_t)b * D_ + d] = acc * (1.f / (float)NPATCH);
    }
}

// ---------------- final LN + head ----------------
__global__ __launch_bounds__(256) void head_k(
    const float* __restrict__ pooled, const float* __restrict__ g,
    const float* __restrict__ bb, const float* __restrict__ hW,
    const float* __restrict__ hb, float* __restrict__ out)
{
    const int b = blockIdx.x;
    __shared__ float row[D_];
    const int tid = threadIdx.x;
    const float v0 = pooled[(size_t)b * D_ + tid];
    const float v1 = pooled[(size_t)b * D_ + tid + 256];
    const float mean = block_sum256(v0 + v1) * (1.f / 512.f);
    const float d0 = v0 - mean, d1 = v1 - mean;
    const float var = block_sum256(d0 * d0 + d1 * d1) * (1.f / 512.f);
    const float rstd = rsqrtf(var + 1e-5f);
    row[tid]       = d0 * rstd * g[tid]       + bb[tid];
    row[tid + 256] = d1 * rstd * g[tid + 256] + bb[tid + 256];
    __syncthreads();
    if (tid < HOR_) {
        float acc = hb[tid];
        for (int kk = 0; kk < D_; kk++) acc = fmaf(row[kk], hW[kk * HOR_ + tid], acc);
        out[(size_t)b * HOR_ + tid] = acc;
    }
}

extern "C" void kernel_launch(void* const* d_in, const int* in_sizes, int n_in,
                              void* d_out, int out_size, void* d_ws, size_t ws_size,
                              hipStream_t stream)
{
    const float* x       = (const float*)d_in[0];
    const float* patch_W = (const float*)d_in[1];
    const float* patch_b = (const float*)d_in[2];
    const float* pos     = (const float*)d_in[3];
    const float* ln1_g   = (const float*)d_in[4];
    const float* ln1_b   = (const float*)d_in[5];
    const float* Wq      = (const float*)d_in[6];
    const float* bq      = (const float*)d_in[7];
    const float* Wk      = (const float*)d_in[8];
    const float* bk      = (const float*)d_in[9];
    const float* Wv      = (const float*)d_in[10];
    const float* bv      = (const float*)d_in[11];
    const float* Wo      = (const float*)d_in[12];
    const float* bo      = (const float*)d_in[13];
    const float* ln2_g   = (const float*)d_in[14];
    const float* ln2_b   = (const float*)d_in[15];
    const float* W1      = (const float*)d_in[16];
    const float* b1      = (const float*)d_in[17];
    const float* W2      = (const float*)d_in[18];
    const float* b2      = (const float*)d_in[19];
    const float* fn_g    = (const float*)d_in[20];
    const float* fn_b    = (const float*)d_in[21];
    const float* head_W  = (const float*)d_in[22];
    const float* head_b  = (const float*)d_in[23];
    float* out = (float*)d_out;

    // ---- workspace layout: converted weights (per-call), then activations ----
    const size_t WELEM  = (size_t)D_ * D_;
    const size_t WFELEM = (size_t)D_ * DFF_;
    bf16* wqkvt = (bf16*)d_ws;                       // [6][1536][512]
    bf16* wot   = wqkvt + (size_t)NLAYER * 3 * WELEM;
    bf16* w1t   = wot   + (size_t)NLAYER * WELEM;    // [6][2048][512]
    bf16* w2t   = w1t   + (size_t)NLAYER * WFELEM;   // [6][512][2048]
    bf16* pwt   = w2t   + (size_t)NLAYER * WFELEM;   // [512][96]
    float* bqkv = (float*)(pwt + (size_t)D_ * KPAD); // [6][1536]
    bf16* xpad  = (bf16*)(bqkv + NLAYER * 3 * D_);   // [NTOK][96]
    char* wend  = (char*)(xpad + (size_t)NTOK_ * KPAD);
    const size_t FIXED = (size_t)(wend - (char*)d_ws);

    // per-token activation bytes: h f32 2048 + hn bf16 1024 + qkv bf16 3072 + ao bf16 1024
    int BC = 16;
    for (int cand = BATCH_; cand >= 16; cand >>= 1) {
        const size_t need = FIXED + (size_t)cand * NPATCH * 7168 + (size_t)cand * 2048;
        if (need <= ws_size) { BC = cand; break; }
    }
    const int nChunks = BATCH_ / BC;
    const int CT = BC * NPATCH;
    const size_t TD = (size_t)CT * D_;

    float* h    = (float*)wend;             // [CT][512] f32
    bf16*  hn   = (bf16*)(h + TD);          // [CT][512] bf16
    bf16*  qkv  = hn + TD;                  // [CT][1536] bf16
    bf16*  ao   = qkv + (size_t)CT * 1536;  // [CT][512] bf16
    bf16*  mid  = qkv;                      // [CT][2048] bf16 aliases qkv+ao
    float* pooled = (float*)(ao + TD);      // [BC][512] f32

    // ---- one-time conversions ----
    transpose_bf16_k<<<dim3(16, 16, NLAYER), 256, 0, stream>>>(
        Wq, wqkvt,                 D_, D_, WELEM, 3 * WELEM);
    transpose_bf16_k<<<dim3(16, 16, NLAYER), 256, 0, stream>>>(
        Wk, wqkvt + WELEM,         D_, D_, WELEM, 3 * WELEM);
    transpose_bf16_k<<<dim3(16, 16, NLAYER), 256, 0, stream>>>(
        Wv, wqkvt + 2 * WELEM,     D_, D_, WELEM, 3 * WELEM);
    transpose_bf16_k<<<dim3(16, 16, NLAYER), 256, 0, stream>>>(
        Wo, wot,                   D_, D_, WELEM, WELEM);
    transpose_bf16_k<<<dim3(64, 16, NLAYER), 256, 0, stream>>>(
        W1, w1t,                   D_, DFF_, WFELEM, WFELEM);
    transpose_bf16_k<<<dim3(16, 64, NLAYER), 256, 0, stream>>>(
        W2, w2t,                   DFF_, D_, WFELEM, WFELEM);
    pwt_k<<<(D_ * KPAD + 255) / 256, 256, 0, stream>>>(patch_W, pwt);
    bqkv_k<<<(NLAYER * 3 * D_ + 255) / 256, 256, 0, stream>>>(bq, bk, bv, bqkv);
    xpad_k<<<((size_t)NTOK_ * KPAD + 255) / 256, 256, 0, stream>>>(x, xpad);

    const dim3 g1(D_ / 128, CT / 128);
    const dim3 gq(3 * D_ / 128, CT / 128);
    const dim3 g2(DFF_ / 128, CT / 128);

    for (int c = 0; c < nChunks; c++) {
        const size_t tok0 = (size_t)c * CT;

        // patch embedding as MFMA GEMM: h = xpad @ pwt^T + pb + pos
        gemm_bf16_k<false, false, false, true><<<g1, 256, 0, stream>>>(
            xpad + tok0 * KPAD, pwt, patch_b, nullptr, pos, h, CT, D_, KPAD);

        for (int l = 0; l < NLAYER; l++) {
            layernorm_bf16_k<<<CT, 256, 0, stream>>>(h, ln1_g + l * D_, ln1_b + l * D_, hn);
            gemm_bf16_k<true, false, false, false><<<gq, 256, 0, stream>>>(
                hn, wqkvt + (size_t)l * 3 * WELEM, bqkv + l * 3 * D_, nullptr, nullptr,
                qkv, CT, 3 * D_, D_);
            attn_k<<<BC * HEADS, 256, 0, stream>>>(qkv, ao);
            gemm_bf16_k<false, false, true, false><<<g1, 256, 0, stream>>>(
                ao, wot + (size_t)l * WELEM, bo + l * D_, h, nullptr, h, CT, D_, D_);
            layernorm_bf16_k<<<CT, 256, 0, stream>>>(h, ln2_g + l * D_, ln2_b + l * D_, hn);
            gemm_bf16_k<true, true, false, false><<<g2, 256, 0, stream>>>(
                hn, w1t + (size_t)l * WFELEM, b1 + l * DFF_, nullptr, nullptr,
                mid, CT, DFF_, D_);
            gemm_bf16_k<false, false, true, false><<<g1, 256, 0, stream>>>(
                mid, w2t + (size_t)l * WFELEM, b2 + l * D_, h, nullptr, h, CT, D_, DFF_);
        }

        meanpool_k<<<BC, 256, 0, stream>>>(h, pooled);
        head_k<<<BC, 256, 0, stream>>>(pooled, fn_g, fn_b, head_W, head_b,
                                       out + (size_t)c * BC * HOR_);
    }
}

// Round 5
// 2572.596 us; speedup vs baseline: 6.3303x; 1.3046x over previous
//
#include <hip/hip_runtime.h>
#include <hip/hip_bf16.h>
#include <math.h>

#define D_      512
#define NPATCH  56
#define DFF_    2048
#define NLAYER  6
#define HEADS   8
#define DH_     64
#define HOR_    24
#define BATCH_  512
#define NTOK_   (BATCH_ * NPATCH)
#define KPAD    96                  // patch K=72 padded to 96 (mult of 32)

typedef __hip_bfloat16 bf16;
typedef __bf16 bf16x8 __attribute__((ext_vector_type(8)));
typedef float  f32x4  __attribute__((ext_vector_type(4)));

__device__ __forceinline__ void gload_lds16(const void* g, void* lds) {
    __builtin_amdgcn_global_load_lds(
        (const __attribute__((address_space(1))) unsigned int*)g,
        (__attribute__((address_space(3))) unsigned int*)lds, 16, 0, 0);
}

// ---------------- block-wide sum over 256 threads ----------------
__device__ __forceinline__ float block_sum256(float v) {
    __shared__ float sm[4];
    const int lane = threadIdx.x & 63;
    const int w    = threadIdx.x >> 6;
    #pragma unroll
    for (int o = 32; o > 0; o >>= 1) v += __shfl_down(v, o);
    __syncthreads();
    if (lane == 0) sm[w] = v;
    __syncthreads();
    return sm[0] + sm[1] + sm[2] + sm[3];
}

// ---------------- transpose + fp32->bf16 with independent layer strides ----------------
__global__ __launch_bounds__(256) void transpose_bf16_k(
    const float* __restrict__ in, bf16* __restrict__ out, int R, int C,
    size_t in_ls, size_t out_ls)
{
    __shared__ float t[32][33];
    in  += (size_t)blockIdx.z * in_ls;
    out += (size_t)blockIdx.z * out_ls;
    const int c0 = blockIdx.x * 32, r0 = blockIdx.y * 32;
    const int x = threadIdx.x & 31, y = threadIdx.x >> 5;
    #pragma unroll
    for (int i = 0; i < 4; i++)
        t[y + i * 8][x] = in[(size_t)(r0 + y + i * 8) * C + c0 + x];
    __syncthreads();
    #pragma unroll
    for (int i = 0; i < 4; i++)
        out[(size_t)(c0 + y + i * 8) * R + r0 + x] = __float2bfloat16(t[x][y + i * 8]);
}

// ---------------- patch_W [72][512] -> bf16 transposed padded [512][96] ----------------
__global__ __launch_bounds__(256) void pwt_k(
    const float* __restrict__ W, bf16* __restrict__ out)
{
    const int idx = blockIdx.x * 256 + threadIdx.x;
    if (idx >= D_ * KPAD) return;
    const int n = idx / KPAD, kk = idx % KPAD;
    out[idx] = (kk < 72) ? __float2bfloat16(W[kk * D_ + n]) : __float2bfloat16(0.f);
}

// ---------------- x [NTOK][72] f32 -> [NTOK][96] bf16 zero-padded ----------------
__global__ __launch_bounds__(256) void xpad_k(
    const float* __restrict__ x, bf16* __restrict__ out)
{
    const size_t idx = (size_t)blockIdx.x * 256 + threadIdx.x;
    if (idx >= (size_t)NTOK_ * KPAD) return;
    const size_t row = idx / KPAD;
    const int kk = (int)(idx - row * KPAD);
    out[idx] = (kk < 72) ? __float2bfloat16(x[row * 72 + kk]) : __float2bfloat16(0.f);
}

// ---------------- concat q/k/v biases -> [NL][1536] f32 ----------------
__global__ __launch_bounds__(256) void bqkv_k(
    const float* __restrict__ bq, const float* __restrict__ bk,
    const float* __restrict__ bv, float* __restrict__ o)
{
    const int idx = blockIdx.x * 256 + threadIdx.x;
    if (idx >= NLAYER * 3 * D_) return;
    const int l = idx / (3 * D_), n = idx % (3 * D_);
    float v;
    if      (n < D_)     v = bq[l * D_ + n];
    else if (n < 2 * D_) v = bk[l * D_ + n - D_];
    else                 v = bv[l * D_ + n - 2 * D_];
    o[idx] = v;
}

// ---------------- LayerNorm fp32 in -> bf16 out ----------------
__global__ __launch_bounds__(256) void layernorm_bf16_k(
    const float* __restrict__ x, const float* __restrict__ g,
    const float* __restrict__ b, bf16* __restrict__ y)
{
    const size_t row = blockIdx.x;
    const float* xr = x + row * D_;
    bf16* yr = y + row * D_;
    const int tid = threadIdx.x;
    const float v0 = xr[tid], v1 = xr[tid + 256];
    const float mean = block_sum256(v0 + v1) * (1.f / 512.f);
    const float d0 = v0 - mean, d1 = v1 - mean;
    const float var = block_sum256(d0 * d0 + d1 * d1) * (1.f / 512.f);
    const float rstd = rsqrtf(var + 1e-5f);
    yr[tid]       = __float2bfloat16(d0 * rstd * g[tid]       + b[tid]);
    yr[tid + 256] = __float2bfloat16(d1 * rstd * g[tid + 256] + b[tid + 256]);
}

// ---------------- bf16 MFMA GEMM (m97 structure): C[M,N] = A[M,K] @ Bt[N,K]^T ----------------
// QKVSPLIT: N=1536; cols 0-1023 (Q,K) -> Cp with row stride 1024; cols 1024+ (V) ->
// vt[b][h][d][p] transposed (b = row/56 local, p = row%56) so attention reads V^T rows.
template<bool OUT_BF16, bool GELU, bool RESID, bool POS, bool QKVSPLIT>
__global__ __launch_bounds__(256, 2) void gemm_bf16_k(
    const bf16* __restrict__ A, const bf16* __restrict__ Bt,
    const float* __restrict__ bias, const float* __restrict__ resid,
    const float* __restrict__ pos, void* __restrict__ Cp,
    bf16* __restrict__ vt, int M, int N, int K)
{
    __shared__ __align__(16) bf16 As[128 * 32];
    __shared__ __align__(16) bf16 Bs[128 * 32];
    const int tid  = threadIdx.x;
    const int wid  = tid >> 6;
    const int lane = tid & 63;
    const int n0 = blockIdx.x * 128;
    const int m0 = blockIdx.y * 128;
    const int wr = wid >> 1, wc = wid & 1;

    f32x4 acc[4][4];
    #pragma unroll
    for (int m = 0; m < 4; m++)
        #pragma unroll
        for (int n = 0; n < 4; n++) acc[m][n] = f32x4{0.f, 0.f, 0.f, 0.f};

    const int rstage = wid * 32 + (lane >> 2);
    const int cstage = (lane & 3) * 8;
    const bf16* gA = A  + (size_t)(m0 + rstage) * K + cstage;
    const bf16* gB = Bt + (size_t)(n0 + rstage) * K + cstage;
    bf16* lA0 = &As[(wid * 2 + 0) * 512];
    bf16* lA1 = &As[(wid * 2 + 1) * 512];
    bf16* lB0 = &Bs[(wid * 2 + 0) * 512];
    bf16* lB1 = &Bs[(wid * 2 + 1) * 512];
    const size_t k16 = (size_t)16 * K;

    const int fr = lane & 15;
    const int kc = (lane >> 4) * 8;
    const int abase = (wr * 64 + fr) * 32 + kc;
    const int bbase = (wc * 64 + fr) * 32 + kc;

    for (int k0 = 0; k0 < K; k0 += 32) {
        gload_lds16(gA + k0,       lA0);
        gload_lds16(gA + k0 + k16, lA1);
        gload_lds16(gB + k0,       lB0);
        gload_lds16(gB + k0 + k16, lB1);
        __syncthreads();
        bf16x8 af[4], bg[4];
        #pragma unroll
        for (int m = 0; m < 4; m++) af[m] = *(const bf16x8*)&As[abase + m * 512];
        #pragma unroll
        for (int n = 0; n < 4; n++) bg[n] = *(const bf16x8*)&Bs[bbase + n * 512];
        #pragma unroll
        for (int m = 0; m < 4; m++)
            #pragma unroll
            for (int n = 0; n < 4; n++)
                acc[m][n] = __builtin_amdgcn_mfma_f32_16x16x32_bf16(af[m], bg[n], acc[m][n], 0, 0, 0);
        __syncthreads();
    }

    const int rq = (lane >> 4) * 4;
    #pragma unroll
    for (int m = 0; m < 4; m++) {
        #pragma unroll
        for (int n = 0; n < 4; n++) {
            const int col = n0 + wc * 64 + n * 16 + fr;
            const float bcol = bias[col];
            #pragma unroll
            for (int j = 0; j < 4; j++) {
                const int row = m0 + wr * 64 + m * 16 + rq + j;
                float c = acc[m][n][j] + bcol;
                if (GELU) {
                    const float xg = c;
                    c = 0.5f * xg * (1.f + tanhf(0.7978845608028654f *
                            (xg + 0.044715f * xg * xg * xg)));
                }
                if (RESID) c += resid[(size_t)row * N + col];
                if (POS)   c += pos[(size_t)(row % NPATCH) * D_ + col];
                if (QKVSPLIT) {
                    if (col < 1024) {
                        ((bf16*)Cp)[(size_t)row * 1024 + col] = __float2bfloat16(c);
                    } else {
                        const int c2 = col - 1024, hh = c2 >> 6, dd = c2 & 63;
                        const int bb = row / NPATCH, pp = row - bb * NPATCH;
                        vt[(((size_t)bb * 8 + hh) * 64 + dd) * 64 + pp] = __float2bfloat16(c);
                    }
                } else if (OUT_BF16) {
                    ((bf16*)Cp)[(size_t)row * N + col] = __float2bfloat16(c);
                } else {
                    ((float*)Cp)[(size_t)row * N + col] = c;
                }
            }
        }
    }
}

// ---------------- MFMA attention: 1 wave per (b,h); no cross-wave sync ----------------
// qk: [CT][1024] bf16 (Q cols 0-511, K cols 512-1023); vt: [BC][8][64][64] V^T; ao out.
__global__ __launch_bounds__(256) void attn_mfma_k(
    const bf16* __restrict__ qk, const bf16* __restrict__ vt,
    bf16* __restrict__ ao)
{
    __shared__ __align__(16) bf16 St[4][64 * 72];   // per-wave P tile, padded rows
    const int tid  = threadIdx.x;
    const int w    = tid >> 6, lane = tid & 63;
    const int bh   = blockIdx.x * 4 + w;
    const int b    = bh >> 3, hh = bh & 7;
    const int fr   = lane & 15;
    const int qg   = lane >> 4;
    const int kc   = qg * 8;

    const bf16* Qb = qk + (size_t)b * NPATCH * 1024 + hh * 64;
    const bf16* Kb = Qb + 512;
    const bf16* Vb = vt + (size_t)bh * 4096;

    // Q/K fragments straight from global (A-frag: row=fr+16m, k=kc+32ks; contiguous 16B)
    bf16x8 qf[4][2], kf[4][2];
    #pragma unroll
    for (int m = 0; m < 4; m++)
        #pragma unroll
        for (int ks = 0; ks < 2; ks++) {
            qf[m][ks] = *(const bf16x8*)&Qb[(size_t)(m * 16 + fr) * 1024 + ks * 32 + kc];
            kf[m][ks] = *(const bf16x8*)&Kb[(size_t)(m * 16 + fr) * 1024 + ks * 32 + kc];
        }

    f32x4 acc[4][4];
    #pragma unroll
    for (int m = 0; m < 4; m++)
        #pragma unroll
        for (int n = 0; n < 4; n++) acc[m][n] = f32x4{0.f, 0.f, 0.f, 0.f};
    #pragma unroll
    for (int ks = 0; ks < 2; ks++)
        #pragma unroll
        for (int m = 0; m < 4; m++)
            #pragma unroll
            for (int n = 0; n < 4; n++)
                acc[m][n] = __builtin_amdgcn_mfma_f32_16x16x32_bf16(qf[m][ks], kf[n][ks], acc[m][n], 0, 0, 0);

    // prefetch V^T B-frags (latency hides under softmax VALU)
    bf16x8 vf[4][2];
    #pragma unroll
    for (int n = 0; n < 4; n++)
        #pragma unroll
        for (int ks = 0; ks < 2; ks++)
            vf[n][ks] = *(const bf16x8*)&Vb[(size_t)(n * 16 + fr) * 64 + ks * 32 + kc];

    // softmax: rows r = 16m + 4qg + j; lane holds cols 16n+fr. Reduce over 16-lane group.
    const float slope = exp2f(-(float)(hh + 1));
    bf16* Sw = St[w];
    #pragma unroll
    for (int m = 0; m < 4; m++) {
        #pragma unroll
        for (int j = 0; j < 4; j++) {
            const int r = m * 16 + qg * 4 + j;
            float s[4];
            #pragma unroll
            for (int n = 0; n < 4; n++) {
                const int col = n * 16 + fr;
                float sv = acc[m][n][j] * 0.125f - slope * fabsf((float)(r - col));
                s[n] = (col >= NPATCH) ? -1e30f : sv;
            }
            float mx = fmaxf(fmaxf(s[0], s[1]), fmaxf(s[2], s[3]));
            mx = fmaxf(mx, __shfl_xor(mx, 1));
            mx = fmaxf(mx, __shfl_xor(mx, 2));
            mx = fmaxf(mx, __shfl_xor(mx, 4));
            mx = fmaxf(mx, __shfl_xor(mx, 8));
            float p[4], sum = 0.f;
            #pragma unroll
            for (int n = 0; n < 4; n++) { p[n] = __expf(s[n] - mx); sum += p[n]; }
            sum += __shfl_xor(sum, 1);
            sum += __shfl_xor(sum, 2);
            sum += __shfl_xor(sum, 4);
            sum += __shfl_xor(sum, 8);
            const float inv = 1.f / sum;
            #pragma unroll
            for (int n = 0; n < 4; n++)
                Sw[r * 72 + n * 16 + fr] = __float2bfloat16(p[n] * inv);
        }
    }

    // PV: A-frags from Sw (contiguous 16B), B-frags = vf. Same-wave LDS dep: compiler waits.
    #pragma unroll
    for (int m = 0; m < 4; m++)
        #pragma unroll
        for (int n = 0; n < 4; n++) acc[m][n] = f32x4{0.f, 0.f, 0.f, 0.f};
    #pragma unroll
    for (int m = 0; m < 4; m++)
        #pragma unroll
        for (int ks = 0; ks < 2; ks++) {
            const bf16x8 pf = *(const bf16x8*)&Sw[(m * 16 + fr) * 72 + ks * 32 + kc];
            #pragma unroll
            for (int n = 0; n < 4; n++)
                acc[m][n] = __builtin_amdgcn_mfma_f32_16x16x32_bf16(pf, vf[n][ks], acc[m][n], 0, 0, 0);
        }

    bf16* Ob = ao + (size_t)b * NPATCH * 512 + hh * 64;
    #pragma unroll
    for (int m = 0; m < 4; m++)
        #pragma unroll
        for (int j = 0; j < 4; j++) {
            const int r = m * 16 + qg * 4 + j;
            if (r < NPATCH)
                #pragma unroll
                for (int n = 0; n < 4; n++)
                    Ob[(size_t)r * 512 + n * 16 + fr] = __float2bfloat16(acc[m][n][j]);
        }
}

// ---------------- mean pool ----------------
__global__ __launch_bounds__(256) void meanpool_k(
    const float* __restrict__ h, float* __restrict__ pooled)
{
    const int b = blockIdx.x;
    for (int d = threadIdx.x; d < D_; d += 256) {
        float acc = 0.f;
        #pragma unroll
        for (int p = 0; p < NPATCH; p++)
            acc += h[(size_t)b * NPATCH * D_ + (size_t)p * D_ + d];
        pooled[(size_t)b * D_ + d] = acc * (1.f / (float)NPATCH);
    }
}

// ---------------- final LN + head ----------------
__global__ __launch_bounds__(256) void head_k(
    const float* __restrict__ pooled, const float* __restrict__ g,
    const float* __restrict__ bb, const float* __restrict__ hW,
    const float* __restrict__ hb, float* __restrict__ out)
{
    const int b = blockIdx.x;
    __shared__ float row[D_];
    const int tid = threadIdx.x;
    const float v0 = pooled[(size_t)b * D_ + tid];
    const float v1 = pooled[(size_t)b * D_ + tid + 256];
    const float mean = block_sum256(v0 + v1) * (1.f / 512.f);
    const float d0 = v0 - mean, d1 = v1 - mean;
    const float var = block_sum256(d0 * d0 + d1 * d1) * (1.f / 512.f);
    const float rstd = rsqrtf(var + 1e-5f);
    row[tid]       = d0 * rstd * g[tid]       + bb[tid];
    row[tid + 256] = d1 * rstd * g[tid + 256] + bb[tid + 256];
    __syncthreads();
    if (tid < HOR_) {
        float acc = hb[tid];
        for (int kk = 0; kk < D_; kk++) acc = fmaf(row[kk], hW[kk * HOR_ + tid], acc);
        out[(size_t)b * HOR_ + tid] = acc;
    }
}

extern "C" void kernel_launch(void* const* d_in, const int* in_sizes, int n_in,
                              void* d_out, int out_size, void* d_ws, size_t ws_size,
                              hipStream_t stream)
{
    const float* x       = (const float*)d_in[0];
    const float* patch_W = (const float*)d_in[1];
    const float* patch_b = (const float*)d_in[2];
    const float* pos     = (const float*)d_in[3];
    const float* ln1_g   = (const float*)d_in[4];
    const float* ln1_b   = (const float*)d_in[5];
    const float* Wq      = (const float*)d_in[6];
    const float* bq      = (const float*)d_in[7];
    const float* Wk      = (const float*)d_in[8];
    const float* bk      = (const float*)d_in[9];
    const float* Wv      = (const float*)d_in[10];
    const float* bv      = (const float*)d_in[11];
    const float* Wo      = (const float*)d_in[12];
    const float* bo      = (const float*)d_in[13];
    const float* ln2_g   = (const float*)d_in[14];
    const float* ln2_b   = (const float*)d_in[15];
    const float* W1      = (const float*)d_in[16];
    const float* b1      = (const float*)d_in[17];
    const float* W2      = (const float*)d_in[18];
    const float* b2      = (const float*)d_in[19];
    const float* fn_g    = (const float*)d_in[20];
    const float* fn_b    = (const float*)d_in[21];
    const float* head_W  = (const float*)d_in[22];
    const float* head_b  = (const float*)d_in[23];
    float* out = (float*)d_out;

    // ---- workspace: converted weights (per-call), then activations ----
    const size_t WELEM  = (size_t)D_ * D_;
    const size_t WFELEM = (size_t)D_ * DFF_;
    bf16* wqkvt = (bf16*)d_ws;                       // [6][1536][512]
    bf16* wot   = wqkvt + (size_t)NLAYER * 3 * WELEM;
    bf16* w1t   = wot   + (size_t)NLAYER * WELEM;    // [6][2048][512]
    bf16* w2t   = w1t   + (size_t)NLAYER * WFELEM;   // [6][512][2048]
    bf16* pwt   = w2t   + (size_t)NLAYER * WFELEM;   // [512][96]
    float* bqkv = (float*)(pwt + (size_t)D_ * KPAD); // [6][1536]
    bf16* xpad  = (bf16*)(bqkv + NLAYER * 3 * D_);   // [NTOK][96]
    char* wend  = (char*)(xpad + (size_t)NTOK_ * KPAD);
    const size_t FIXED = (size_t)(wend - (char*)d_ws);

    // per batch-row bytes: 56*(h 2048 + hn 1024 + qk 2048 + ao 1024) + vt 65536 + pooled 2048
    int BC = 16;
    for (int cand = BATCH_; cand >= 16; cand >>= 1) {
        const size_t need = FIXED + (size_t)cand * (56 * 6144 + 65536 + 2048);
        if (need <= ws_size) { BC = cand; break; }
    }
    const int nChunks = BATCH_ / BC;
    const int CT = BC * NPATCH;
    const size_t TD = (size_t)CT * D_;

    float* h    = (float*)wend;                   // [CT][512] f32
    bf16*  hn   = (bf16*)(h + TD);                // [CT][512] bf16
    bf16*  qk   = hn + TD;                        // [CT][1024] bf16
    bf16*  ao   = qk + (size_t)CT * 1024;         // [CT][512] bf16 (qk OOB-read spill lands here)
    bf16*  vt   = ao + TD;                        // [BC][8][64][64] bf16
    bf16*  mid  = qk;                             // [CT][2048] bf16 aliases qk+ao+vt (all dead at FFN)
    float* pooled = (float*)(vt + (size_t)BC * 8 * 64 * 64);   // [BC][512]

    // ---- one-time conversions ----
    transpose_bf16_k<<<dim3(16, 16, NLAYER), 256, 0, stream>>>(
        Wq, wqkvt,                 D_, D_, WELEM, 3 * WELEM);
    transpose_bf16_k<<<dim3(16, 16, NLAYER), 256, 0, stream>>>(
        Wk, wqkvt + WELEM,         D_, D_, WELEM, 3 * WELEM);
    transpose_bf16_k<<<dim3(16, 16, NLAYER), 256, 0, stream>>>(
        Wv, wqkvt + 2 * WELEM,     D_, D_, WELEM, 3 * WELEM);
    transpose_bf16_k<<<dim3(16, 16, NLAYER), 256, 0, stream>>>(
        Wo, wot,                   D_, D_, WELEM, WELEM);
    transpose_bf16_k<<<dim3(64, 16, NLAYER), 256, 0, stream>>>(
        W1, w1t,                   D_, DFF_, WFELEM, WFELEM);
    transpose_bf16_k<<<dim3(16, 64, NLAYER), 256, 0, stream>>>(
        W2, w2t,                   DFF_, D_, WFELEM, WFELEM);
    pwt_k<<<(D_ * KPAD + 255) / 256, 256, 0, stream>>>(patch_W, pwt);
    bqkv_k<<<(NLAYER * 3 * D_ + 255) / 256, 256, 0, stream>>>(bq, bk, bv, bqkv);
    xpad_k<<<((size_t)NTOK_ * KPAD + 255) / 256, 256, 0, stream>>>(x, xpad);

    const dim3 g1(D_ / 128, CT / 128);
    const dim3 gq(3 * D_ / 128, CT / 128);
    const dim3 g2(DFF_ / 128, CT / 128);

    for (int c = 0; c < nChunks; c++) {
        const size_t tok0 = (size_t)c * CT;

        gemm_bf16_k<false, false, false, true, false><<<g1, 256, 0, stream>>>(
            xpad + tok0 * KPAD, pwt, patch_b, nullptr, pos, h, nullptr, CT, D_, KPAD);

        for (int l = 0; l < NLAYER; l++) {
            layernorm_bf16_k<<<CT, 256, 0, stream>>>(h, ln1_g + l * D_, ln1_b + l * D_, hn);
            gemm_bf16_k<true, false, false, false, true><<<gq, 256, 0, stream>>>(
                hn, wqkvt + (size_t)l * 3 * WELEM, bqkv + l * 3 * D_, nullptr, nullptr,
                qk, vt, CT, 3 * D_, D_);
            attn_mfma_k<<<BC * 2, 256, 0, stream>>>(qk, vt, ao);
            gemm_bf16_k<false, false, true, false, false><<<g1, 256, 0, stream>>>(
                ao, wot + (size_t)l * WELEM, bo + l * D_, h, nullptr, h, nullptr, CT, D_, D_);
            layernorm_bf16_k<<<CT, 256, 0, stream>>>(h, ln2_g + l * D_, ln2_b + l * D_, hn);
            gemm_bf16_k<true, true, false, false, false><<<g2, 256, 0, stream>>>(
                hn, w1t + (size_t)l * WFELEM, b1 + l * DFF_, nullptr, nullptr,
                mid, nullptr, CT, DFF_, D_);
            gemm_bf16_k<false, false, true, false, false><<<g1, 256, 0, stream>>>(
                mid, w2t + (size_t)l * WFELEM, b2 + l * D_, h, nullptr, h, nullptr, CT, D_, DFF_);
        }

        meanpool_k<<<BC, 256, 0, stream>>>(h, pooled);
        head_k<<<BC, 256, 0, stream>>>(pooled, fn_g, fn_b, head_W, head_b,
                                       out + (size_t)c * BC * HOR_);
    }
}

// Round 6
// 2396.270 us; speedup vs baseline: 6.7961x; 1.0736x over previous
//
#include <hip/hip_runtime.h>
#include <hip/hip_bf16.h>
#include <math.h>

#define D_      512
#define NPATCH  56
#define DFF_    2048
#define NLAYER  6
#define HEADS   8
#define DH_     64
#define HOR_    24
#define BATCH_  512
#define NTOK_   (BATCH_ * NPATCH)
#define KPAD    96                  // patch K=72 padded to 96 (mult of 32)

typedef __hip_bfloat16 bf16;
typedef __bf16 bf16x8 __attribute__((ext_vector_type(8)));
typedef float  f32x4  __attribute__((ext_vector_type(4)));

__device__ __forceinline__ void gload_lds16(const void* g, void* lds) {
    __builtin_amdgcn_global_load_lds(
        (const __attribute__((address_space(1))) unsigned int*)g,
        (__attribute__((address_space(3))) unsigned int*)lds, 16, 0, 0);
}

// ---------------- block-wide sum over 256 threads ----------------
__device__ __forceinline__ float block_sum256(float v) {
    __shared__ float sm[4];
    const int lane = threadIdx.x & 63;
    const int w    = threadIdx.x >> 6;
    #pragma unroll
    for (int o = 32; o > 0; o >>= 1) v += __shfl_down(v, o);
    __syncthreads();
    if (lane == 0) sm[w] = v;
    __syncthreads();
    return sm[0] + sm[1] + sm[2] + sm[3];
}

// fast tanh-GELU: 0.5x(1+tanh(.79788(x+.044715x^3))) = x - x*rcp(1+exp(2u))
__device__ __forceinline__ float gelu_fast(float xg) {
    const float e = __expf(1.5957691216057308f * (xg + 0.044715f * xg * xg * xg));
    return xg - xg * __builtin_amdgcn_rcpf(1.f + e);
}

// ---------------- transpose + fp32->bf16 with independent layer strides ----------------
__global__ __launch_bounds__(256) void transpose_bf16_k(
    const float* __restrict__ in, bf16* __restrict__ out, int R, int C,
    size_t in_ls, size_t out_ls)
{
    __shared__ float t[32][33];
    in  += (size_t)blockIdx.z * in_ls;
    out += (size_t)blockIdx.z * out_ls;
    const int c0 = blockIdx.x * 32, r0 = blockIdx.y * 32;
    const int x = threadIdx.x & 31, y = threadIdx.x >> 5;
    #pragma unroll
    for (int i = 0; i < 4; i++)
        t[y + i * 8][x] = in[(size_t)(r0 + y + i * 8) * C + c0 + x];
    __syncthreads();
    #pragma unroll
    for (int i = 0; i < 4; i++)
        out[(size_t)(c0 + y + i * 8) * R + r0 + x] = __float2bfloat16(t[x][y + i * 8]);
}

// ---------------- patch_W [72][512] -> bf16 transposed padded [512][96] ----------------
__global__ __launch_bounds__(256) void pwt_k(
    const float* __restrict__ W, bf16* __restrict__ out)
{
    const int idx = blockIdx.x * 256 + threadIdx.x;
    if (idx >= D_ * KPAD) return;
    const int n = idx / KPAD, kk = idx % KPAD;
    out[idx] = (kk < 72) ? __float2bfloat16(W[kk * D_ + n]) : __float2bfloat16(0.f);
}

// ---------------- x [NTOK][72] f32 -> [NTOK][96] bf16 zero-padded ----------------
__global__ __launch_bounds__(256) void xpad_k(
    const float* __restrict__ x, bf16* __restrict__ out)
{
    const size_t idx = (size_t)blockIdx.x * 256 + threadIdx.x;
    if (idx >= (size_t)NTOK_ * KPAD) return;
    const size_t row = idx / KPAD;
    const int kk = (int)(idx - row * KPAD);
    out[idx] = (kk < 72) ? __float2bfloat16(x[row * 72 + kk]) : __float2bfloat16(0.f);
}

// ---------------- concat q/k/v biases -> [NL][1536] f32 ----------------
__global__ __launch_bounds__(256) void bqkv_k(
    const float* __restrict__ bq, const float* __restrict__ bk,
    const float* __restrict__ bv, float* __restrict__ o)
{
    const int idx = blockIdx.x * 256 + threadIdx.x;
    if (idx >= NLAYER * 3 * D_) return;
    const int l = idx / (3 * D_), n = idx % (3 * D_);
    float v;
    if      (n < D_)     v = bq[l * D_ + n];
    else if (n < 2 * D_) v = bk[l * D_ + n - D_];
    else                 v = bv[l * D_ + n - 2 * D_];
    o[idx] = v;
}

// ---------------- LayerNorm fp32 in -> bf16 out ----------------
__global__ __launch_bounds__(256) void layernorm_bf16_k(
    const float* __restrict__ x, const float* __restrict__ g,
    const float* __restrict__ b, bf16* __restrict__ y)
{
    const size_t row = blockIdx.x;
    const float* xr = x + row * D_;
    bf16* yr = y + row * D_;
    const int tid = threadIdx.x;
    const float v0 = xr[tid], v1 = xr[tid + 256];
    const float mean = block_sum256(v0 + v1) * (1.f / 512.f);
    const float d0 = v0 - mean, d1 = v1 - mean;
    const float var = block_sum256(d0 * d0 + d1 * d1) * (1.f / 512.f);
    const float rstd = rsqrtf(var + 1e-5f);
    yr[tid]       = __float2bfloat16(d0 * rstd * g[tid]       + b[tid]);
    yr[tid + 256] = __float2bfloat16(d1 * rstd * g[tid + 256] + b[tid + 256]);
}

// ---------------- bf16 MFMA GEMM: C[M,N] = A[M,K] @ Bt[N,K]^T ----------------
// 128x128 tile, BK=64 (two 32-wide half-buffers staged per barrier pair), K%32==0.
// QKVSPLIT: N=1536; cols 0-1023 (Q,K) -> Cp row stride 1024; cols 1024+ (V) -> vt transposed.
template<bool OUT_BF16, bool GELU, bool RESID, bool POS, bool QKVSPLIT>
__global__ __launch_bounds__(256, 2) void gemm_bf16_k(
    const bf16* __restrict__ A, const bf16* __restrict__ Bt,
    const float* __restrict__ bias, const float* __restrict__ resid,
    const float* __restrict__ pos, void* __restrict__ Cp,
    bf16* __restrict__ vt, int M, int N, int K)
{
    __shared__ __align__(16) bf16 As[2][128 * 32];
    __shared__ __align__(16) bf16 Bs[2][128 * 32];
    const int tid  = threadIdx.x;
    const int wid  = tid >> 6;
    const int lane = tid & 63;
    const int n0 = blockIdx.x * 128;
    const int m0 = blockIdx.y * 128;
    const int wr = wid >> 1, wc = wid & 1;

    f32x4 acc[4][4];
    #pragma unroll
    for (int m = 0; m < 4; m++)
        #pragma unroll
        for (int n = 0; n < 4; n++) acc[m][n] = f32x4{0.f, 0.f, 0.f, 0.f};

    const int rstage = wid * 32 + (lane >> 2);
    const int cstage = (lane & 3) * 8;
    const bf16* gA = A  + (size_t)(m0 + rstage) * K + cstage;
    const bf16* gB = Bt + (size_t)(n0 + rstage) * K + cstage;
    const size_t k16 = (size_t)16 * K;
    const int s0 = (wid * 2 + 0) * 512, s1 = (wid * 2 + 1) * 512;

    const int fr = lane & 15;
    const int kc = (lane >> 4) * 8;
    const int abase = (wr * 64 + fr) * 32 + kc;
    const int bbase = (wc * 64 + fr) * 32 + kc;

    int k0 = 0;
    for (; k0 + 64 <= K; k0 += 64) {
        gload_lds16(gA + k0,            &As[0][s0]);
        gload_lds16(gA + k0 + k16,      &As[0][s1]);
        gload_lds16(gB + k0,            &Bs[0][s0]);
        gload_lds16(gB + k0 + k16,      &Bs[0][s1]);
        gload_lds16(gA + k0 + 32,       &As[1][s0]);
        gload_lds16(gA + k0 + 32 + k16, &As[1][s1]);
        gload_lds16(gB + k0 + 32,       &Bs[1][s0]);
        gload_lds16(gB + k0 + 32 + k16, &Bs[1][s1]);
        __syncthreads();
        #pragma unroll
        for (int s = 0; s < 2; s++) {
            bf16x8 af[4], bg[4];
            #pragma unroll
            for (int m = 0; m < 4; m++) af[m] = *(const bf16x8*)&As[s][abase + m * 512];
            #pragma unroll
            for (int n = 0; n < 4; n++) bg[n] = *(const bf16x8*)&Bs[s][bbase + n * 512];
            #pragma unroll
            for (int m = 0; m < 4; m++)
                #pragma unroll
                for (int n = 0; n < 4; n++)
                    acc[m][n] = __builtin_amdgcn_mfma_f32_16x16x32_bf16(af[m], bg[n], acc[m][n], 0, 0, 0);
        }
        __syncthreads();
    }
    if (k0 < K) {   // 32-wide tail
        gload_lds16(gA + k0,       &As[0][s0]);
        gload_lds16(gA + k0 + k16, &As[0][s1]);
        gload_lds16(gB + k0,       &Bs[0][s0]);
        gload_lds16(gB + k0 + k16, &Bs[0][s1]);
        __syncthreads();
        bf16x8 af[4], bg[4];
        #pragma unroll
        for (int m = 0; m < 4; m++) af[m] = *(const bf16x8*)&As[0][abase + m * 512];
        #pragma unroll
        for (int n = 0; n < 4; n++) bg[n] = *(const bf16x8*)&Bs[0][bbase + n * 512];
        #pragma unroll
        for (int m = 0; m < 4; m++)
            #pragma unroll
            for (int n = 0; n < 4; n++)
                acc[m][n] = __builtin_amdgcn_mfma_f32_16x16x32_bf16(af[m], bg[n], acc[m][n], 0, 0, 0);
    }

    const int rq = (lane >> 4) * 4;
    #pragma unroll
    for (int m = 0; m < 4; m++) {
        #pragma unroll
        for (int n = 0; n < 4; n++) {
            const int col = n0 + wc * 64 + n * 16 + fr;
            const float bcol = bias[col];
            #pragma unroll
            for (int j = 0; j < 4; j++) {
                const int row = m0 + wr * 64 + m * 16 + rq + j;
                float c = acc[m][n][j] + bcol;
                if (GELU)  c = gelu_fast(c);
                if (RESID) c += resid[(size_t)row * N + col];
                if (POS)   c += pos[(size_t)(row % NPATCH) * D_ + col];
                if (QKVSPLIT) {
                    if (col < 1024) {
                        ((bf16*)Cp)[(size_t)row * 1024 + col] = __float2bfloat16(c);
                    } else {
                        const int c2 = col - 1024, hh = c2 >> 6, dd = c2 & 63;
                        const int bb = row / NPATCH, pp = row - bb * NPATCH;
                        vt[(((size_t)bb * 8 + hh) * 64 + dd) * 64 + pp] = __float2bfloat16(c);
                    }
                } else if (OUT_BF16) {
                    ((bf16*)Cp)[(size_t)row * N + col] = __float2bfloat16(c);
                } else {
                    ((float*)Cp)[(size_t)row * N + col] = c;
                }
            }
        }
    }
}

// ---------------- MFMA attention: 1 wave per (b,h); no cross-wave sync ----------------
__global__ __launch_bounds__(256) void attn_mfma_k(
    const bf16* __restrict__ qk, const bf16* __restrict__ vt,
    bf16* __restrict__ ao)
{
    __shared__ __align__(16) bf16 St[4][64 * 72];
    const int tid  = threadIdx.x;
    const int w    = tid >> 6, lane = tid & 63;
    const int bh   = blockIdx.x * 4 + w;
    const int b    = bh >> 3, hh = bh & 7;
    const int fr   = lane & 15;
    const int qg   = lane >> 4;
    const int kc   = qg * 8;

    const bf16* Qb = qk + (size_t)b * NPATCH * 1024 + hh * 64;
    const bf16* Kb = Qb + 512;
    const bf16* Vb = vt + (size_t)bh * 4096;

    bf16x8 qf[4][2], kf[4][2];
    #pragma unroll
    for (int m = 0; m < 4; m++)
        #pragma unroll
        for (int ks = 0; ks < 2; ks++) {
            qf[m][ks] = *(const bf16x8*)&Qb[(size_t)(m * 16 + fr) * 1024 + ks * 32 + kc];
            kf[m][ks] = *(const bf16x8*)&Kb[(size_t)(m * 16 + fr) * 1024 + ks * 32 + kc];
        }

    f32x4 acc[4][4];
    #pragma unroll
    for (int m = 0; m < 4; m++)
        #pragma unroll
        for (int n = 0; n < 4; n++) acc[m][n] = f32x4{0.f, 0.f, 0.f, 0.f};
    #pragma unroll
    for (int ks = 0; ks < 2; ks++)
        #pragma unroll
        for (int m = 0; m < 4; m++)
            #pragma unroll
            for (int n = 0; n < 4; n++)
                acc[m][n] = __builtin_amdgcn_mfma_f32_16x16x32_bf16(qf[m][ks], kf[n][ks], acc[m][n], 0, 0, 0);

    bf16x8 vf[4][2];
    #pragma unroll
    for (int n = 0; n < 4; n++)
        #pragma unroll
        for (int ks = 0; ks < 2; ks++)
            vf[n][ks] = *(const bf16x8*)&Vb[(size_t)(n * 16 + fr) * 64 + ks * 32 + kc];

    const float slope = exp2f(-(float)(hh + 1));
    bf16* Sw = St[w];
    #pragma unroll
    for (int m = 0; m < 4; m++) {
        #pragma unroll
        for (int j = 0; j < 4; j++) {
            const int r = m * 16 + qg * 4 + j;
            float s[4];
            #pragma unroll
            for (int n = 0; n < 4; n++) {
                const int col = n * 16 + fr;
                float sv = acc[m][n][j] * 0.125f - slope * fabsf((float)(r - col));
                s[n] = (col >= NPATCH) ? -1e30f : sv;
            }
            float mx = fmaxf(fmaxf(s[0], s[1]), fmaxf(s[2], s[3]));
            mx = fmaxf(mx, __shfl_xor(mx, 1));
            mx = fmaxf(mx, __shfl_xor(mx, 2));
            mx = fmaxf(mx, __shfl_xor(mx, 4));
            mx = fmaxf(mx, __shfl_xor(mx, 8));
            float p[4], sum = 0.f;
            #pragma unroll
            for (int n = 0; n < 4; n++) { p[n] = __expf(s[n] - mx); sum += p[n]; }
            sum += __shfl_xor(sum, 1);
            sum += __shfl_xor(sum, 2);
            sum += __shfl_xor(sum, 4);
            sum += __shfl_xor(sum, 8);
            const float inv = 1.f / sum;
            #pragma unroll
            for (int n = 0; n < 4; n++)
                Sw[r * 72 + n * 16 + fr] = __float2bfloat16(p[n] * inv);
        }
    }

    #pragma unroll
    for (int m = 0; m < 4; m++)
        #pragma unroll
        for (int n = 0; n < 4; n++) acc[m][n] = f32x4{0.f, 0.f, 0.f, 0.f};
    #pragma unroll
    for (int m = 0; m < 4; m++)
        #pragma unroll
        for (int ks = 0; ks < 2; ks++) {
            const bf16x8 pf = *(const bf16x8*)&Sw[(m * 16 + fr) * 72 + ks * 32 + kc];
            #pragma unroll
            for (int n = 0; n < 4; n++)
                acc[m][n] = __builtin_amdgcn_mfma_f32_16x16x32_bf16(pf, vf[n][ks], acc[m][n], 0, 0, 0);
        }

    bf16* Ob = ao + (size_t)b * NPATCH * 512 + hh * 64;
    #pragma unroll
    for (int m = 0; m < 4; m++)
        #pragma unroll
        for (int j = 0; j < 4; j++) {
            const int r = m * 16 + qg * 4 + j;
            if (r < NPATCH)
                #pragma unroll
                for (int n = 0; n < 4; n++)
                    Ob[(size_t)r * 512 + n * 16 + fr] = __float2bfloat16(acc[m][n][j]);
        }
}

// ---------------- mean pool ----------------
__global__ __launch_bounds__(256) void meanpool_k(
    const float* __restrict__ h, float* __restrict__ pooled)
{
    const int b = blockIdx.x;
    for (int d = threadIdx.x; d < D_; d += 256) {
        float acc = 0.f;
        #pragma unroll
        for (int p = 0; p < NPATCH; p++)
            acc += h[(size_t)b * NPATCH * D_ + (size_t)p * D_ + d];
        pooled[(size_t)b * D_ + d] = acc * (1.f / (float)NPATCH);
    }
}

// ---------------- final LN + head ----------------
__global__ __launch_bounds__(256) void head_k(
    const float* __restrict__ pooled, const float* __restrict__ g,
    const float* __restrict__ bb, const float* __restrict__ hW,
    const float* __restrict__ hb, float* __restrict__ out)
{
    const int b = blockIdx.x;
    __shared__ float row[D_];
    const int tid = threadIdx.x;
    const float v0 = pooled[(size_t)b * D_ + tid];
    const float v1 = pooled[(size_t)b * D_ + tid + 256];
    const float mean = block_sum256(v0 + v1) * (1.f / 512.f);
    const float d0 = v0 - mean, d1 = v1 - mean;
    const float var = block_sum256(d0 * d0 + d1 * d1) * (1.f / 512.f);
    const float rstd = rsqrtf(var + 1e-5f);
    row[tid]       = d0 * rstd * g[tid]       + bb[tid];
    row[tid + 256] = d1 * rstd * g[tid + 256] + bb[tid + 256];
    __syncthreads();
    if (tid < HOR_) {
        float acc = hb[tid];
        for (int kk = 0; kk < D_; kk++) acc = fmaf(row[kk], hW[kk * HOR_ + tid], acc);
        out[(size_t)b * HOR_ + tid] = acc;
    }
}

extern "C" void kernel_launch(void* const* d_in, const int* in_sizes, int n_in,
                              void* d_out, int out_size, void* d_ws, size_t ws_size,
                              hipStream_t stream)
{
    const float* x       = (const float*)d_in[0];
    const float* patch_W = (const float*)d_in[1];
    const float* patch_b = (const float*)d_in[2];
    const float* pos     = (const float*)d_in[3];
    const float* ln1_g   = (const float*)d_in[4];
    const float* ln1_b   = (const float*)d_in[5];
    const float* Wq      = (const float*)d_in[6];
    const float* bq      = (const float*)d_in[7];
    const float* Wk      = (const float*)d_in[8];
    const float* bk      = (const float*)d_in[9];
    const float* Wv      = (const float*)d_in[10];
    const float* bv      = (const float*)d_in[11];
    const float* Wo      = (const float*)d_in[12];
    const float* bo      = (const float*)d_in[13];
    const float* ln2_g   = (const float*)d_in[14];
    const float* ln2_b   = (const float*)d_in[15];
    const float* W1      = (const float*)d_in[16];
    const float* b1      = (const float*)d_in[17];
    const float* W2      = (const float*)d_in[18];
    const float* b2      = (const float*)d_in[19];
    const float* fn_g    = (const float*)d_in[20];
    const float* fn_b    = (const float*)d_in[21];
    const float* head_W  = (const float*)d_in[22];
    const float* head_b  = (const float*)d_in[23];
    float* out = (float*)d_out;

    // ---- workspace: converted weights (per-call), then activations ----
    const size_t WELEM  = (size_t)D_ * D_;
    const size_t WFELEM = (size_t)D_ * DFF_;
    bf16* wqkvt = (bf16*)d_ws;                       // [6][1536][512]
    bf16* wot   = wqkvt + (size_t)NLAYER * 3 * WELEM;
    bf16* w1t   = wot   + (size_t)NLAYER * WELEM;    // [6][2048][512]
    bf16* w2t   = w1t   + (size_t)NLAYER * WFELEM;   // [6][512][2048]
    bf16* pwt   = w2t   + (size_t)NLAYER * WFELEM;   // [512][96]
    float* bqkv = (float*)(pwt + (size_t)D_ * KPAD); // [6][1536]
    bf16* xpad  = (bf16*)(bqkv + NLAYER * 3 * D_);   // [NTOK][96]
    char* wend  = (char*)(xpad + (size_t)NTOK_ * KPAD);
    const size_t FIXED = (size_t)(wend - (char*)d_ws);

    int BC = 16;
    for (int cand = BATCH_; cand >= 16; cand >>= 1) {
        const size_t need = FIXED + (size_t)cand * (56 * 6144 + 65536 + 2048);
        if (need <= ws_size) { BC = cand; break; }
    }
    const int nChunks = BATCH_ / BC;
    const int CT = BC * NPATCH;
    const size_t TD = (size_t)CT * D_;

    float* h    = (float*)wend;                   // [CT][512] f32
    bf16*  hn   = (bf16*)(h + TD);                // [CT][512] bf16
    bf16*  qk   = hn + TD;                        // [CT][1024] bf16
    bf16*  ao   = qk + (size_t)CT * 1024;         // [CT][512] bf16
    bf16*  vt   = ao + TD;                        // [BC][8][64][64] bf16
    bf16*  mid  = qk;                             // [CT][2048] bf16 aliases qk+ao+vt
    float* pooled = (float*)(vt + (size_t)BC * 8 * 64 * 64);   // [BC][512]

    // ---- one-time conversions ----
    transpose_bf16_k<<<dim3(16, 16, NLAYER), 256, 0, stream>>>(
        Wq, wqkvt,                 D_, D_, WELEM, 3 * WELEM);
    transpose_bf16_k<<<dim3(16, 16, NLAYER), 256, 0, stream>>>(
        Wk, wqkvt + WELEM,         D_, D_, WELEM, 3 * WELEM);
    transpose_bf16_k<<<dim3(16, 16, NLAYER), 256, 0, stream>>>(
        Wv, wqkvt + 2 * WELEM,     D_, D_, WELEM, 3 * WELEM);
    transpose_bf16_k<<<dim3(16, 16, NLAYER), 256, 0, stream>>>(
        Wo, wot,                   D_, D_, WELEM, WELEM);
    transpose_bf16_k<<<dim3(64, 16, NLAYER), 256, 0, stream>>>(
        W1, w1t,                   D_, DFF_, WFELEM, WFELEM);
    transpose_bf16_k<<<dim3(16, 64, NLAYER), 256, 0, stream>>>(
        W2, w2t,                   DFF_, D_, WFELEM, WFELEM);
    pwt_k<<<(D_ * KPAD + 255) / 256, 256, 0, stream>>>(patch_W, pwt);
    bqkv_k<<<(NLAYER * 3 * D_ + 255) / 256, 256, 0, stream>>>(bq, bk, bv, bqkv);
    xpad_k<<<((size_t)NTOK_ * KPAD + 255) / 256, 256, 0, stream>>>(x, xpad);

    const dim3 g1(D_ / 128, CT / 128);
    const dim3 gq(3 * D_ / 128, CT / 128);
    const dim3 g2(DFF_ / 128, CT / 128);

    for (int c = 0; c < nChunks; c++) {
        const size_t tok0 = (size_t)c * CT;

        gemm_bf16_k<false, false, false, true, false><<<g1, 256, 0, stream>>>(
            xpad + tok0 * KPAD, pwt, patch_b, nullptr, pos, h, nullptr, CT, D_, KPAD);

        for (int l = 0; l < NLAYER; l++) {
            layernorm_bf16_k<<<CT, 256, 0, stream>>>(h, ln1_g + l * D_, ln1_b + l * D_, hn);
            gemm_bf16_k<true, false, false, false, true><<<gq, 256, 0, stream>>>(
                hn, wqkvt + (size_t)l * 3 * WELEM, bqkv + l * 3 * D_, nullptr, nullptr,
                qk, vt, CT, 3 * D_, D_);
            attn_mfma_k<<<BC * 2, 256, 0, stream>>>(qk, vt, ao);
            gemm_bf16_k<false, false, true, false, false><<<g1, 256, 0, stream>>>(
                ao, wot + (size_t)l * WELEM, bo + l * D_, h, nullptr, h, nullptr, CT, D_, D_);
            layernorm_bf16_k<<<CT, 256, 0, stream>>>(h, ln2_g + l * D_, ln2_b + l * D_, hn);
            gemm_bf16_k<true, true, false, false, false><<<g2, 256, 0, stream>>>(
                hn, w1t + (size_t)l * WFELEM, b1 + l * DFF_, nullptr, nullptr,
                mid, nullptr, CT, DFF_, D_);
            gemm_bf16_k<false, false, true, false, false><<<g1, 256, 0, stream>>>(
                mid, w2t + (size_t)l * WFELEM, b2 + l * D_, h, nullptr, h, nullptr, CT, D_, DFF_);
        }

        meanpool_k<<<BC, 256, 0, stream>>>(h, pooled);
        head_k<<<BC, 256, 0, stream>>>(pooled, fn_g, fn_b, head_W, head_b,
                                       out + (size_t)c * BC * HOR_);
    }
}

// Round 7
// 2284.184 us; speedup vs baseline: 7.1296x; 1.0491x over previous
//
#include <hip/hip_runtime.h>
#include <hip/hip_bf16.h>
#include <math.h>

#define D_      512
#define NPATCH  56
#define DFF_    2048
#define NLAYER  6
#define HEADS   8
#define DH_     64
#define HOR_    24
#define BATCH_  512
#define NTOK_   (BATCH_ * NPATCH)
#define KPAD    96                  // patch K=72 padded to 96 (mult of 32)

typedef __hip_bfloat16 bf16;
typedef __bf16 bf16x8 __attribute__((ext_vector_type(8)));
typedef float  f32x4  __attribute__((ext_vector_type(4)));

__device__ __forceinline__ void gload_lds16(const void* g, void* lds) {
    __builtin_amdgcn_global_load_lds(
        (const __attribute__((address_space(1))) unsigned int*)g,
        (__attribute__((address_space(3))) unsigned int*)lds, 16, 0, 0);
}

// ---------------- block-wide sum over 256 threads ----------------
__device__ __forceinline__ float block_sum256(float v) {
    __shared__ float sm[4];
    const int lane = threadIdx.x & 63;
    const int w    = threadIdx.x >> 6;
    #pragma unroll
    for (int o = 32; o > 0; o >>= 1) v += __shfl_down(v, o);
    __syncthreads();
    if (lane == 0) sm[w] = v;
    __syncthreads();
    return sm[0] + sm[1] + sm[2] + sm[3];
}

// fast tanh-GELU: 0.5x(1+tanh(.79788(x+.044715x^3))) = x - x*rcp(1+exp(2u))
__device__ __forceinline__ float gelu_fast(float xg) {
    const float e = __expf(1.5957691216057308f * (xg + 0.044715f * xg * xg * xg));
    return xg - xg * __builtin_amdgcn_rcpf(1.f + e);
}

// ---------------- transpose + fp32->bf16 with independent layer strides ----------------
__global__ __launch_bounds__(256) void transpose_bf16_k(
    const float* __restrict__ in, bf16* __restrict__ out, int R, int C,
    size_t in_ls, size_t out_ls)
{
    __shared__ float t[32][33];
    in  += (size_t)blockIdx.z * in_ls;
    out += (size_t)blockIdx.z * out_ls;
    const int c0 = blockIdx.x * 32, r0 = blockIdx.y * 32;
    const int x = threadIdx.x & 31, y = threadIdx.x >> 5;
    #pragma unroll
    for (int i = 0; i < 4; i++)
        t[y + i * 8][x] = in[(size_t)(r0 + y + i * 8) * C + c0 + x];
    __syncthreads();
    #pragma unroll
    for (int i = 0; i < 4; i++)
        out[(size_t)(c0 + y + i * 8) * R + r0 + x] = __float2bfloat16(t[x][y + i * 8]);
}

// ---------------- patch_W [72][512] -> bf16 transposed padded [512][96] ----------------
__global__ __launch_bounds__(256) void pwt_k(
    const float* __restrict__ W, bf16* __restrict__ out)
{
    const int idx = blockIdx.x * 256 + threadIdx.x;
    if (idx >= D_ * KPAD) return;
    const int n = idx / KPAD, kk = idx % KPAD;
    out[idx] = (kk < 72) ? __float2bfloat16(W[kk * D_ + n]) : __float2bfloat16(0.f);
}

// ---------------- x [NTOK][72] f32 -> [NTOK][96] bf16 zero-padded ----------------
__global__ __launch_bounds__(256) void xpad_k(
    const float* __restrict__ x, bf16* __restrict__ out)
{
    const size_t idx = (size_t)blockIdx.x * 256 + threadIdx.x;
    if (idx >= (size_t)NTOK_ * KPAD) return;
    const size_t row = idx / KPAD;
    const int kk = (int)(idx - row * KPAD);
    out[idx] = (kk < 72) ? __float2bfloat16(x[row * 72 + kk]) : __float2bfloat16(0.f);
}

// ---------------- concat q/k/v biases -> [NL][1536] f32 ----------------
__global__ __launch_bounds__(256) void bqkv_k(
    const float* __restrict__ bq, const float* __restrict__ bk,
    const float* __restrict__ bv, float* __restrict__ o)
{
    const int idx = blockIdx.x * 256 + threadIdx.x;
    if (idx >= NLAYER * 3 * D_) return;
    const int l = idx / (3 * D_), n = idx % (3 * D_);
    float v;
    if      (n < D_)     v = bq[l * D_ + n];
    else if (n < 2 * D_) v = bk[l * D_ + n - D_];
    else                 v = bv[l * D_ + n - 2 * D_];
    o[idx] = v;
}

// ---------------- LayerNorm fp32 in -> bf16 out ----------------
__global__ __launch_bounds__(256) void layernorm_bf16_k(
    const float* __restrict__ x, const float* __restrict__ g,
    const float* __restrict__ b, bf16* __restrict__ y)
{
    const size_t row = blockIdx.x;
    const float* xr = x + row * D_;
    bf16* yr = y + row * D_;
    const int tid = threadIdx.x;
    const float v0 = xr[tid], v1 = xr[tid + 256];
    const float mean = block_sum256(v0 + v1) * (1.f / 512.f);
    const float d0 = v0 - mean, d1 = v1 - mean;
    const float var = block_sum256(d0 * d0 + d1 * d1) * (1.f / 512.f);
    const float rstd = rsqrtf(var + 1e-5f);
    yr[tid]       = __float2bfloat16(d0 * rstd * g[tid]       + b[tid]);
    yr[tid + 256] = __float2bfloat16(d1 * rstd * g[tid + 256] + b[tid + 256]);
}

// ---------------- bf16 MFMA GEMM: C[M,N] = A[M,K] @ Bt[N,K]^T ----------------
// 128x128 tile, BK=32, double-buffered 2-phase prefetch (STAGE next || compute cur),
// one barrier per K-step. 1D grid with bijective XCD swizzle (n-fastest per XCD chunk).
// QKVSPLIT: N=1536; cols 0-1023 (Q,K) -> Cp row stride 1024; cols 1024+ (V) -> vt transposed.
template<bool OUT_BF16, bool GELU, bool RESID, bool POS, bool QKVSPLIT>
__global__ __launch_bounds__(256, 4) void gemm_bf16_k(
    const bf16* __restrict__ A, const bf16* __restrict__ Bt,
    const float* __restrict__ bias, const float* __restrict__ resid,
    const float* __restrict__ pos, void* __restrict__ Cp,
    bf16* __restrict__ vt, int M, int N, int K, int nx)
{
    __shared__ __align__(16) bf16 As[2][128 * 32];
    __shared__ __align__(16) bf16 Bs[2][128 * 32];
    const int tid  = threadIdx.x;
    const int wid  = tid >> 6;
    const int lane = tid & 63;

    // bijective XCD swizzle (m204): contiguous swz chunk per XCD, n-tile fastest
    const int nwg = gridDim.x;
    const int q8 = nwg >> 3, r8 = nwg & 7;
    const int xcd = blockIdx.x & 7, idx8 = blockIdx.x >> 3;
    const int swz = (xcd < r8 ? xcd * (q8 + 1) : r8 * (q8 + 1) + (xcd - r8) * q8) + idx8;
    const int n0 = (swz % nx) * 128;
    const int m0 = (swz / nx) * 128;
    const int wr = wid >> 1, wc = wid & 1;

    f32x4 acc[4][4];
    #pragma unroll
    for (int m = 0; m < 4; m++)
        #pragma unroll
        for (int n = 0; n < 4; n++) acc[m][n] = f32x4{0.f, 0.f, 0.f, 0.f};

    const int rstage = wid * 32 + (lane >> 2);
    const int cstage = (lane & 3) * 8;
    const bf16* gA = A  + (size_t)(m0 + rstage) * K + cstage;
    const bf16* gB = Bt + (size_t)(n0 + rstage) * K + cstage;
    const size_t k16 = (size_t)16 * K;
    const int s0 = (wid * 2 + 0) * 512, s1 = (wid * 2 + 1) * 512;

    const int fr = lane & 15;
    const int kc = (lane >> 4) * 8;
    const int abase = (wr * 64 + fr) * 32 + kc;
    const int bbase = (wc * 64 + fr) * 32 + kc;

    // prologue: stage K-step 0 into buf 0
    gload_lds16(gA,       &As[0][s0]);
    gload_lds16(gA + k16, &As[0][s1]);
    gload_lds16(gB,       &Bs[0][s0]);
    gload_lds16(gB + k16, &Bs[0][s1]);
    __syncthreads();

    const int nt = K >> 5;
    int cur = 0;
    for (int t = 0; t < nt; t++) {
        if (t + 1 < nt) {               // prefetch next K-step into other buffer
            const int kn = (t + 1) << 5;
            gload_lds16(gA + kn,       &As[cur ^ 1][s0]);
            gload_lds16(gA + kn + k16, &As[cur ^ 1][s1]);
            gload_lds16(gB + kn,       &Bs[cur ^ 1][s0]);
            gload_lds16(gB + kn + k16, &Bs[cur ^ 1][s1]);
        }
        bf16x8 af[4], bg[4];
        #pragma unroll
        for (int m = 0; m < 4; m++) af[m] = *(const bf16x8*)&As[cur][abase + m * 512];
        #pragma unroll
        for (int n = 0; n < 4; n++) bg[n] = *(const bf16x8*)&Bs[cur][bbase + n * 512];
        #pragma unroll
        for (int m = 0; m < 4; m++)
            #pragma unroll
            for (int n = 0; n < 4; n++)
                acc[m][n] = __builtin_amdgcn_mfma_f32_16x16x32_bf16(af[m], bg[n], acc[m][n], 0, 0, 0);
        __syncthreads();                // drains prefetch (flew during MFMAs) + read fence
        cur ^= 1;
    }

    const int rq = (lane >> 4) * 4;
    #pragma unroll
    for (int m = 0; m < 4; m++) {
        #pragma unroll
        for (int n = 0; n < 4; n++) {
            const int col = n0 + wc * 64 + n * 16 + fr;
            const float bcol = bias[col];
            #pragma unroll
            for (int j = 0; j < 4; j++) {
                const int row = m0 + wr * 64 + m * 16 + rq + j;
                float c = acc[m][n][j] + bcol;
                if (GELU)  c = gelu_fast(c);
                if (RESID) c += resid[(size_t)row * N + col];
                if (POS)   c += pos[(size_t)(row % NPATCH) * D_ + col];
                if (QKVSPLIT) {
                    if (col < 1024) {
                        ((bf16*)Cp)[(size_t)row * 1024 + col] = __float2bfloat16(c);
                    } else {
                        const int c2 = col - 1024, hh = c2 >> 6, dd = c2 & 63;
                        const int bb = row / NPATCH, pp = row - bb * NPATCH;
                        vt[(((size_t)bb * 8 + hh) * 64 + dd) * 64 + pp] = __float2bfloat16(c);
                    }
                } else if (OUT_BF16) {
                    ((bf16*)Cp)[(size_t)row * N + col] = __float2bfloat16(c);
                } else {
                    ((float*)Cp)[(size_t)row * N + col] = c;
                }
            }
        }
    }
}

// ---------------- MFMA attention: 1 wave per (b,h); no cross-wave sync ----------------
__global__ __launch_bounds__(256) void attn_mfma_k(
    const bf16* __restrict__ qk, const bf16* __restrict__ vt,
    bf16* __restrict__ ao)
{
    __shared__ __align__(16) bf16 St[4][64 * 72];
    const int tid  = threadIdx.x;
    const int w    = tid >> 6, lane = tid & 63;
    const int bh   = blockIdx.x * 4 + w;
    const int b    = bh >> 3, hh = bh & 7;
    const int fr   = lane & 15;
    const int qg   = lane >> 4;
    const int kc   = qg * 8;

    const bf16* Qb = qk + (size_t)b * NPATCH * 1024 + hh * 64;
    const bf16* Kb = Qb + 512;
    const bf16* Vb = vt + (size_t)bh * 4096;

    bf16x8 qf[4][2], kf[4][2];
    #pragma unroll
    for (int m = 0; m < 4; m++)
        #pragma unroll
        for (int ks = 0; ks < 2; ks++) {
            qf[m][ks] = *(const bf16x8*)&Qb[(size_t)(m * 16 + fr) * 1024 + ks * 32 + kc];
            kf[m][ks] = *(const bf16x8*)&Kb[(size_t)(m * 16 + fr) * 1024 + ks * 32 + kc];
        }

    f32x4 acc[4][4];
    #pragma unroll
    for (int m = 0; m < 4; m++)
        #pragma unroll
        for (int n = 0; n < 4; n++) acc[m][n] = f32x4{0.f, 0.f, 0.f, 0.f};
    #pragma unroll
    for (int ks = 0; ks < 2; ks++)
        #pragma unroll
        for (int m = 0; m < 4; m++)
            #pragma unroll
            for (int n = 0; n < 4; n++)
                acc[m][n] = __builtin_amdgcn_mfma_f32_16x16x32_bf16(qf[m][ks], kf[n][ks], acc[m][n], 0, 0, 0);

    bf16x8 vf[4][2];
    #pragma unroll
    for (int n = 0; n < 4; n++)
        #pragma unroll
        for (int ks = 0; ks < 2; ks++)
            vf[n][ks] = *(const bf16x8*)&Vb[(size_t)(n * 16 + fr) * 64 + ks * 32 + kc];

    const float slope = exp2f(-(float)(hh + 1));
    bf16* Sw = St[w];
    #pragma unroll
    for (int m = 0; m < 4; m++) {
        #pragma unroll
        for (int j = 0; j < 4; j++) {
            const int r = m * 16 + qg * 4 + j;
            float s[4];
            #pragma unroll
            for (int n = 0; n < 4; n++) {
                const int col = n * 16 + fr;
                float sv = acc[m][n][j] * 0.125f - slope * fabsf((float)(r - col));
                s[n] = (col >= NPATCH) ? -1e30f : sv;
            }
            float mx = fmaxf(fmaxf(s[0], s[1]), fmaxf(s[2], s[3]));
            mx = fmaxf(mx, __shfl_xor(mx, 1));
            mx = fmaxf(mx, __shfl_xor(mx, 2));
            mx = fmaxf(mx, __shfl_xor(mx, 4));
            mx = fmaxf(mx, __shfl_xor(mx, 8));
            float p[4], sum = 0.f;
            #pragma unroll
            for (int n = 0; n < 4; n++) { p[n] = __expf(s[n] - mx); sum += p[n]; }
            sum += __shfl_xor(sum, 1);
            sum += __shfl_xor(sum, 2);
            sum += __shfl_xor(sum, 4);
            sum += __shfl_xor(sum, 8);
            const float inv = 1.f / sum;
            #pragma unroll
            for (int n = 0; n < 4; n++)
                Sw[r * 72 + n * 16 + fr] = __float2bfloat16(p[n] * inv);
        }
    }

    #pragma unroll
    for (int m = 0; m < 4; m++)
        #pragma unroll
        for (int n = 0; n < 4; n++) acc[m][n] = f32x4{0.f, 0.f, 0.f, 0.f};
    #pragma unroll
    for (int m = 0; m < 4; m++)
        #pragma unroll
        for (int ks = 0; ks < 2; ks++) {
            const bf16x8 pf = *(const bf16x8*)&Sw[(m * 16 + fr) * 72 + ks * 32 + kc];
            #pragma unroll
            for (int n = 0; n < 4; n++)
                acc[m][n] = __builtin_amdgcn_mfma_f32_16x16x32_bf16(pf, vf[n][ks], acc[m][n], 0, 0, 0);
        }

    bf16* Ob = ao + (size_t)b * NPATCH * 512 + hh * 64;
    #pragma unroll
    for (int m = 0; m < 4; m++)
        #pragma unroll
        for (int j = 0; j < 4; j++) {
            const int r = m * 16 + qg * 4 + j;
            if (r < NPATCH)
                #pragma unroll
                for (int n = 0; n < 4; n++)
                    Ob[(size_t)r * 512 + n * 16 + fr] = __float2bfloat16(acc[m][n][j]);
        }
}

// ---------------- mean pool ----------------
__global__ __launch_bounds__(256) void meanpool_k(
    const float* __restrict__ h, float* __restrict__ pooled)
{
    const int b = blockIdx.x;
    for (int d = threadIdx.x; d < D_; d += 256) {
        float acc = 0.f;
        #pragma unroll
        for (int p = 0; p < NPATCH; p++)
            acc += h[(size_t)b * NPATCH * D_ + (size_t)p * D_ + d];
        pooled[(size_t)b * D_ + d] = acc * (1.f / (float)NPATCH);
    }
}

// ---------------- final LN + head ----------------
__global__ __launch_bounds__(256) void head_k(
    const float* __restrict__ pooled, const float* __restrict__ g,
    const float* __restrict__ bb, const float* __restrict__ hW,
    const float* __restrict__ hb, float* __restrict__ out)
{
    const int b = blockIdx.x;
    __shared__ float row[D_];
    const int tid = threadIdx.x;
    const float v0 = pooled[(size_t)b * D_ + tid];
    const float v1 = pooled[(size_t)b * D_ + tid + 256];
    const float mean = block_sum256(v0 + v1) * (1.f / 512.f);
    const float d0 = v0 - mean, d1 = v1 - mean;
    const float var = block_sum256(d0 * d0 + d1 * d1) * (1.f / 512.f);
    const float rstd = rsqrtf(var + 1e-5f);
    row[tid]       = d0 * rstd * g[tid]       + bb[tid];
    row[tid + 256] = d1 * rstd * g[tid + 256] + bb[tid + 256];
    __syncthreads();
    if (tid < HOR_) {
        float acc = hb[tid];
        for (int kk = 0; kk < D_; kk++) acc = fmaf(row[kk], hW[kk * HOR_ + tid], acc);
        out[(size_t)b * HOR_ + tid] = acc;
    }
}

extern "C" void kernel_launch(void* const* d_in, const int* in_sizes, int n_in,
                              void* d_out, int out_size, void* d_ws, size_t ws_size,
                              hipStream_t stream)
{
    const float* x       = (const float*)d_in[0];
    const float* patch_W = (const float*)d_in[1];
    const float* patch_b = (const float*)d_in[2];
    const float* pos     = (const float*)d_in[3];
    const float* ln1_g   = (const float*)d_in[4];
    const float* ln1_b   = (const float*)d_in[5];
    const float* Wq      = (const float*)d_in[6];
    const float* bq      = (const float*)d_in[7];
    const float* Wk      = (const float*)d_in[8];
    const float* bk      = (const float*)d_in[9];
    const float* Wv      = (const float*)d_in[10];
    const float* bv      = (const float*)d_in[11];
    const float* Wo      = (const float*)d_in[12];
    const float* bo      = (const float*)d_in[13];
    const float* ln2_g   = (const float*)d_in[14];
    const float* ln2_b   = (const float*)d_in[15];
    const float* W1      = (const float*)d_in[16];
    const float* b1      = (const float*)d_in[17];
    const float* W2      = (const float*)d_in[18];
    const float* b2      = (const float*)d_in[19];
    const float* fn_g    = (const float*)d_in[20];
    const float* fn_b    = (const float*)d_in[21];
    const float* head_W  = (const float*)d_in[22];
    const float* head_b  = (const float*)d_in[23];
    float* out = (float*)d_out;

    // ---- workspace: converted weights (per-call), then activations ----
    const size_t WELEM  = (size_t)D_ * D_;
    const size_t WFELEM = (size_t)D_ * DFF_;
    bf16* wqkvt = (bf16*)d_ws;                       // [6][1536][512]
    bf16* wot   = wqkvt + (size_t)NLAYER * 3 * WELEM;
    bf16* w1t   = wot   + (size_t)NLAYER * WELEM;    // [6][2048][512]
    bf16* w2t   = w1t   + (size_t)NLAYER * WFELEM;   // [6][512][2048]
    bf16* pwt   = w2t   + (size_t)NLAYER * WFELEM;   // [512][96]
    float* bqkv = (float*)(pwt + (size_t)D_ * KPAD); // [6][1536]
    bf16* xpad  = (bf16*)(bqkv + NLAYER * 3 * D_);   // [NTOK][96]
    char* wend  = (char*)(xpad + (size_t)NTOK_ * KPAD);
    const size_t FIXED = (size_t)(wend - (char*)d_ws);

    int BC = 16;
    for (int cand = BATCH_; cand >= 16; cand >>= 1) {
        const size_t need = FIXED + (size_t)cand * (56 * 6144 + 65536 + 2048);
        if (need <= ws_size) { BC = cand; break; }
    }
    const int nChunks = BATCH_ / BC;
    const int CT = BC * NPATCH;
    const size_t TD = (size_t)CT * D_;

    float* h    = (float*)wend;                   // [CT][512] f32
    bf16*  hn   = (bf16*)(h + TD);                // [CT][512] bf16
    bf16*  qk   = hn + TD;                        // [CT][1024] bf16
    bf16*  ao   = qk + (size_t)CT * 1024;         // [CT][512] bf16
    bf16*  vt   = ao + TD;                        // [BC][8][64][64] bf16
    bf16*  mid  = qk;                             // [CT][2048] bf16 aliases qk+ao+vt
    float* pooled = (float*)(vt + (size_t)BC * 8 * 64 * 64);   // [BC][512]

    // ---- one-time conversions ----
    transpose_bf16_k<<<dim3(16, 16, NLAYER), 256, 0, stream>>>(
        Wq, wqkvt,                 D_, D_, WELEM, 3 * WELEM);
    transpose_bf16_k<<<dim3(16, 16, NLAYER), 256, 0, stream>>>(
        Wk, wqkvt + WELEM,         D_, D_, WELEM, 3 * WELEM);
    transpose_bf16_k<<<dim3(16, 16, NLAYER), 256, 0, stream>>>(
        Wv, wqkvt + 2 * WELEM,     D_, D_, WELEM, 3 * WELEM);
    transpose_bf16_k<<<dim3(16, 16, NLAYER), 256, 0, stream>>>(
        Wo, wot,                   D_, D_, WELEM, WELEM);
    transpose_bf16_k<<<dim3(64, 16, NLAYER), 256, 0, stream>>>(
        W1, w1t,                   D_, DFF_, WFELEM, WFELEM);
    transpose_bf16_k<<<dim3(16, 64, NLAYER), 256, 0, stream>>>(
        W2, w2t,                   DFF_, D_, WFELEM, WFELEM);
    pwt_k<<<(D_ * KPAD + 255) / 256, 256, 0, stream>>>(patch_W, pwt);
    bqkv_k<<<(NLAYER * 3 * D_ + 255) / 256, 256, 0, stream>>>(bq, bk, bv, bqkv);
    xpad_k<<<((size_t)NTOK_ * KPAD + 255) / 256, 256, 0, stream>>>(x, xpad);

    const int g1n = (D_ / 128) * (CT / 128);        // N-tiles x M-tiles, %8==0
    const int gqn = (3 * D_ / 128) * (CT / 128);
    const int g2n = (DFF_ / 128) * (CT / 128);

    for (int c = 0; c < nChunks; c++) {
        const size_t tok0 = (size_t)c * CT;

        gemm_bf16_k<false, false, false, true, false><<<g1n, 256, 0, stream>>>(
            xpad + tok0 * KPAD, pwt, patch_b, nullptr, pos, h, nullptr,
            CT, D_, KPAD, D_ / 128);

        for (int l = 0; l < NLAYER; l++) {
            layernorm_bf16_k<<<CT, 256, 0, stream>>>(h, ln1_g + l * D_, ln1_b + l * D_, hn);
            gemm_bf16_k<true, false, false, false, true><<<gqn, 256, 0, stream>>>(
                hn, wqkvt + (size_t)l * 3 * WELEM, bqkv + l * 3 * D_, nullptr, nullptr,
                qk, vt, CT, 3 * D_, D_, 3 * D_ / 128);
            attn_mfma_k<<<BC * 2, 256, 0, stream>>>(qk, vt, ao);
            gemm_bf16_k<false, false, true, false, false><<<g1n, 256, 0, stream>>>(
                ao, wot + (size_t)l * WELEM, bo + l * D_, h, nullptr, h, nullptr,
                CT, D_, D_, D_ / 128);
            layernorm_bf16_k<<<CT, 256, 0, stream>>>(h, ln2_g + l * D_, ln2_b + l * D_, hn);
            gemm_bf16_k<true, true, false, false, false><<<g2n, 256, 0, stream>>>(
                hn, w1t + (size_t)l * WFELEM, b1 + l * DFF_, nullptr, nullptr,
                mid, nullptr, CT, DFF_, D_, DFF_ / 128);
            gemm_bf16_k<false, false, true, false, false><<<g1n, 256, 0, stream>>>(
                mid, w2t + (size_t)l * WFELEM, b2 + l * D_, h, nullptr, h, nullptr,
                CT, D_, DFF_, D_ / 128);
        }

        meanpool_k<<<BC, 256, 0, stream>>>(h, pooled);
        head_k<<<BC, 256, 0, stream>>>(pooled, fn_g, fn_b, head_W, head_b,
                                       out + (size_t)c * BC * HOR_);
    }
}